// Round 5
// baseline (149.785 us; speedup 1.0000x reference)
//
#include <hip/hip_runtime.h>
#include <hip/hip_bf16.h>

// dsfa_former: (1) causal full attention + (2) Linformer attention.
// Inputs fp32, outputs fp32. Internal bf16 MFMA, exp2 softmax (no-max:
// scores bounded, softmax is scale-free in fp32).
// B=4, N=2048, H=8, d=32, kproj=256.
//
// Round-15: straggler-tail attack on k_attn. Profile: Occupancy 18%
// time-avg despite full residency at launch => duration governed by the
// longest per-wave chain (m=31 waves: ~16 serial chunks). Change: 8-way
// k-split (512 thr/block, 8 waves; max chain 8 chunks), boundary chunks
// to waves 7/6, 8-partial LDS combine (34 KB), epilogue split by output
// column-half across wave pairs. Linformer packs 2 old blocks per
// 512-thread block. Grid 1536x512.
// Round-14 retained: linproj 8-wave ping-pong, prep packed converts.
// Round-11 retained: raw v_exp_f32, ones-MFMA softmax denominator,
// b128 packed LDS combine, Linformer deferred 1/l normalization.
// Round-10 retained: quad-tile blocks, ping-pong prefetch, S^T trick.
//
// Fragment layouts (learn_hip m89/m91/m120):
//   C/D: per-lane row = quad*4 + reg, col = lane&15
//   A:   lane holds A[m = lane&15][k = quad*8 + j], j=0..7
//   B:   lane holds B[k = quad*8 + j][n = lane&15]

typedef __bf16 bf16x8 __attribute__((ext_vector_type(8)));
typedef __bf16 bf16x2 __attribute__((ext_vector_type(2)));
typedef float f32x4 __attribute__((ext_vector_type(4)));

union BF8 { uint4 u4; ushort us[8]; bf16x8 b; unsigned u32[4]; };

constexpr int B_ = 4, N_ = 2048, H_ = 8, D_ = 32, KP_ = 256, BH_ = 32;
constexpr float SCL2 = 0.25505654442633533f;  // (1/sqrt(32)) * log2(e)
constexpr int NFULL = 1024;                   // causal blocks
constexpr int CHK = 32 * D_;                  // K chunk stride (ushorts)

__device__ __forceinline__ ushort f2bf(float f) {
  unsigned u = __builtin_bit_cast(unsigned, f);
  return (ushort)((u + 0x7FFFu + ((u >> 16) & 1u)) >> 16);
}
// pack two floats -> bf16 pair (lo = first arg)
__device__ __forceinline__ unsigned pkbf(float f0, float f1) {
#if __has_builtin(__builtin_amdgcn_cvt_pk_bf16_f32)
  bf16x2 r = __builtin_amdgcn_cvt_pk_bf16_f32(f0, f1);
  return __builtin_bit_cast(unsigned, r);
#else
  unsigned u0 = __builtin_bit_cast(unsigned, f0) + 0x8000u;
  unsigned u1 = __builtin_bit_cast(unsigned, f1) + 0x8000u;
  return __builtin_amdgcn_perm(u1, u0, 0x07060302);  // [u1.hi : u0.hi]
#endif
}
__device__ __forceinline__ float bflo(unsigned u) {
  return __builtin_bit_cast(float, u << 16);
}
__device__ __forceinline__ float bfhi(unsigned u) {
  return __builtin_bit_cast(float, u & 0xFFFF0000u);
}
// raw v_exp_f32: scores bounded, no -inf fed in, denormal output flushes
// to 0 which is exactly what softmax wants.
__device__ __forceinline__ float ex2(float x) {
#if __has_builtin(__builtin_amdgcn_exp2f)
  return __builtin_amdgcn_exp2f(x);
#else
  return exp2f(x);
#endif
}

__device__ __forceinline__ void load8_bf(const float* __restrict__ p,
                                         float scale, BF8& hi) {
  float4 a = *reinterpret_cast<const float4*>(p);
  float4 b = *reinterpret_cast<const float4*>(p + 4);
  float x[8] = {a.x, a.y, a.z, a.w, b.x, b.y, b.z, b.w};
#pragma unroll
  for (int i = 0; i < 8; ++i) hi.us[i] = f2bf(x[i] * scale);
}

// ---------------------------------------------------------------------------
// Fused prep. Flat grid 1280 blocks of 256:
//   idx < 1024: K -> KH[bh][n][e] bf16, K -> Kt[bh][e][n], V -> Vt[bh][e][n]
//   idx >= 1024: E -> Et[KP][N] bf16 / F -> Ft (256 blocks)
// ---------------------------------------------------------------------------
__global__ __launch_bounds__(256) void k_prep(const float* __restrict__ K,
                                              const float* __restrict__ V,
                                              const float* __restrict__ E,
                                              const float* __restrict__ F,
                                              ushort* __restrict__ KH,
                                              ushort* __restrict__ Kt,
                                              ushort* __restrict__ Vt,
                                              ushort* __restrict__ Et,
                                              ushort* __restrict__ Ft) {
  __shared__ alignas(16) ushort S[4224];
  const int idx = blockIdx.x;
  const int t = threadIdx.x;
  if (idx < 1024) {
    ushort* Tk = S;            // [e][n_local] stride 66
    ushort* Tv = S + 2112;
    const int bh = idx >> 5, b = bh >> 3, h = bh & 7;
    const int n0 = (idx & 31) * 64;
    {
      const int row = t >> 2, e8 = (t & 3) * 8;
      const size_t gbase = ((size_t)(b * N_ + n0 + row) * H_ + h) * D_ + e8;
      float4 k0 = *reinterpret_cast<const float4*>(K + gbase);
      float4 k1 = *reinterpret_cast<const float4*>(K + gbase + 4);
      float4 v0 = *reinterpret_cast<const float4*>(V + gbase);
      float4 v1 = *reinterpret_cast<const float4*>(V + gbase + 4);
      float kk[8] = {k0.x,k0.y,k0.z,k0.w,k1.x,k1.y,k1.z,k1.w};
      float vv[8] = {v0.x,v0.y,v0.z,v0.w,v1.x,v1.y,v1.z,v1.w};
      BF8 xh, vh;
#pragma unroll
      for (int i = 0; i < 4; ++i) {
        xh.u32[i] = pkbf(kk[2 * i], kk[2 * i + 1]);
        vh.u32[i] = pkbf(vv[2 * i], vv[2 * i + 1]);
      }
#pragma unroll
      for (int i = 0; i < 8; ++i) {
        Tk[(e8 + i) * 66 + row] = xh.us[i];
        Tv[(e8 + i) * 66 + row] = vh.us[i];
      }
      *reinterpret_cast<uint4*>(KH + ((size_t)bh * N_ + n0 + row) * D_ + e8) = xh.u4;
    }
    __syncthreads();
    {
      const int e = t >> 3, n8 = (t & 7) * 8;
      BF8 xk, xv;
#pragma unroll
      for (int i = 0; i < 8; ++i) {
        xk.us[i] = Tk[e * 66 + n8 + i];
        xv.us[i] = Tv[e * 66 + n8 + i];
      }
      const size_t ob = ((size_t)bh * D_ + e) * N_ + n0 + n8;
      *reinterpret_cast<uint4*>(Kt + ob) = xk.u4;
      *reinterpret_cast<uint4*>(Vt + ob) = xv.u4;
    }
  } else {
    const int j = idx - 1024;
    const float* src = (j >> 7) ? F : E;
    ushort* dst = (j >> 7) ? Ft : Et;
    const int jj = j & 127;
    const int n0 = (jj & 31) * 64, kp0 = (jj >> 5) * 64;
    ushort* T = S;  // [kp_local][n_local] stride 66
    {
      const int n = t >> 2, c16 = (t & 3) * 16;
      const size_t gbase = (size_t)(n0 + n) * KP_ + kp0 + c16;
#pragma unroll
      for (int q = 0; q < 4; ++q) {
        float4 x = *reinterpret_cast<const float4*>(src + gbase + q * 4);
        const unsigned u01 = pkbf(x.x, x.y), u23 = pkbf(x.z, x.w);
        T[(c16 + q * 4 + 0) * 66 + n] = (ushort)u01;
        T[(c16 + q * 4 + 1) * 66 + n] = (ushort)(u01 >> 16);
        T[(c16 + q * 4 + 2) * 66 + n] = (ushort)u23;
        T[(c16 + q * 4 + 3) * 66 + n] = (ushort)(u23 >> 16);
      }
    }
    __syncthreads();
    {
      const int kp = t >> 2, n16 = (t & 3) * 16;
      BF8 x0, x1;
#pragma unroll
      for (int i = 0; i < 8; ++i) {
        x0.us[i] = T[kp * 66 + n16 + i];
        x1.us[i] = T[kp * 66 + n16 + 8 + i];
      }
      const size_t ob = (size_t)(kp0 + kp) * N_ + n0 + n16;
      *reinterpret_cast<uint4*>(dst + ob) = x0.u4;
      *reinterpret_cast<uint4*>(dst + ob + 8) = x1.u4;
    }
  }
}

// ---------------------------------------------------------------------------
// Kernel: Kp[bh][kp][e] (bf16) and Vpt[bh][e][kp]. Flat grid 512 blocks of
// 512 threads (8 waves, N/8 per wave), XCD-pinned bh, ping-pong prefetch,
// LDS combine over 8 partials.
// ---------------------------------------------------------------------------
__global__ __launch_bounds__(512) void k_linproj(const ushort* __restrict__ Et,
                                                 const ushort* __restrict__ Ft,
                                                 const ushort* __restrict__ Kt,
                                                 const ushort* __restrict__ Vt,
                                                 ushort* __restrict__ Kp,
                                                 ushort* __restrict__ Vpt) {
  __shared__ float L[8][64][16];  // 32 KB
  const int id = blockIdx.x;
  const int bh = (id & 7) + 8 * ((id >> 3) & 3);   // XCD pinning
  const int kp16 = (id >> 5) * 16;
  const int t = threadIdx.x;
  const int w = t >> 6, lane = t & 63, quad = lane >> 4, l15 = lane & 15;
  const int nbase = w * (N_ / 8);                  // 256 per wave

  const ushort* eA = Et + (size_t)(kp16 + l15) * N_ + nbase + quad * 8;
  const ushort* fA = Ft + (size_t)(kp16 + l15) * N_ + nbase + quad * 8;
  const ushort* kB0 = Kt + ((size_t)bh * D_ + l15) * N_ + nbase + quad * 8;
  const ushort* kB1 = kB0 + (size_t)16 * N_;
  const ushort* vB0 = Vt + ((size_t)bh * D_ + l15) * N_ + nbase + quad * 8;
  const ushort* vB1 = vB0 + (size_t)16 * N_;

  f32x4 accK0 = {0.f,0.f,0.f,0.f}, accK1 = {0.f,0.f,0.f,0.f};
  f32x4 accV0 = {0.f,0.f,0.f,0.f}, accV1 = {0.f,0.f,0.f,0.f};

  BF8 e0, f0, k00, k10, v00, v10;   // buffer A
  BF8 e1, f1, k01, k11, v01, v11;   // buffer B

#define LPLD(E, F, K0, K1, V0, V1, NO)                                \
  do {                                                                \
    (E).u4 = *reinterpret_cast<const uint4*>(eA + (NO));              \
    (F).u4 = *reinterpret_cast<const uint4*>(fA + (NO));              \
    (K0).u4 = *reinterpret_cast<const uint4*>(kB0 + (NO));            \
    (K1).u4 = *reinterpret_cast<const uint4*>(kB1 + (NO));            \
    (V0).u4 = *reinterpret_cast<const uint4*>(vB0 + (NO));            \
    (V1).u4 = *reinterpret_cast<const uint4*>(vB1 + (NO));            \
  } while (0)
#define LPMM(E, F, K0, K1, V0, V1)                                            \
  do {                                                                        \
    accK0 = __builtin_amdgcn_mfma_f32_16x16x32_bf16((E).b, (K0).b, accK0, 0, 0, 0); \
    accK1 = __builtin_amdgcn_mfma_f32_16x16x32_bf16((E).b, (K1).b, accK1, 0, 0, 0); \
    accV0 = __builtin_amdgcn_mfma_f32_16x16x32_bf16((F).b, (V0).b, accV0, 0, 0, 0); \
    accV1 = __builtin_amdgcn_mfma_f32_16x16x32_bf16((F).b, (V1).b, accV1, 0, 0, 0); \
  } while (0)

  LPLD(e0, f0, k00, k10, v00, v10, 0);
  LPLD(e1, f1, k01, k11, v01, v11, 32);
#pragma unroll
  for (int p = 0; p < 3; ++p) {
    LPMM(e0, f0, k00, k10, v00, v10);
    LPLD(e0, f0, k00, k10, v00, v10, (2 * p + 2) * 32);
    LPMM(e1, f1, k01, k11, v01, v11);
    LPLD(e1, f1, k01, k11, v01, v11, (2 * p + 3) * 32);
  }
  LPMM(e0, f0, k00, k10, v00, v10);
  LPMM(e1, f1, k01, k11, v01, v11);
#undef LPLD
#undef LPMM

#pragma unroll
  for (int r = 0; r < 4; ++r) {
    L[w][lane][r]      = accK0[r];
    L[w][lane][4 + r]  = accK1[r];
    L[w][lane][8 + r]  = accV0[r];
    L[w][lane][12 + r] = accV1[r];
  }
  __syncthreads();
  if (w < 4) {
#pragma unroll
    for (int r = 0; r < 4; ++r) {
      const float v = ((L[0][lane][w * 4 + r] + L[1][lane][w * 4 + r]) +
                       (L[2][lane][w * 4 + r] + L[3][lane][w * 4 + r])) +
                      ((L[4][lane][w * 4 + r] + L[5][lane][w * 4 + r]) +
                       (L[6][lane][w * 4 + r] + L[7][lane][w * 4 + r]));
      const int kp = kp16 + quad * 4 + r;
      if (w == 0)      Kp[((size_t)bh * KP_ + kp) * D_ + l15]       = f2bf(v);
      else if (w == 1) Kp[((size_t)bh * KP_ + kp) * D_ + 16 + l15]  = f2bf(v);
      else if (w == 2) Vpt[((size_t)bh * D_ + l15) * KP_ + kp]      = f2bf(v);
      else             Vpt[((size_t)bh * D_ + 16 + l15) * KP_ + kp] = f2bf(v);
    }
  }
}

// ---------------------------------------------------------------------------
// Fused attention. Flat grid 1536 blocks of 512 (8 waves):
//   idx < 1024: causal full attention, quad-tile block (q rows [64m,64m+64)).
//     bh = (idx&7)+8*((idx>>3)&3) (XCD pinning), m = 31-(idx>>5) (LPT).
//     Waves k-split chunks [0,2m) 8 ways; wave 7 takes boundary chunk 2m,
//     wave 6 takes chunk 2m+1. 8-partial LDS combine (34 KB); epilogue
//     splits each tile's output column-halves across wave pairs.
//   idx >= 1024: Linformer attention (512 blocks, 2 old blocks each).
// ---------------------------------------------------------------------------
__global__ __launch_bounds__(512, 4) void k_attn(const float* __restrict__ Q,
                                                 const ushort* __restrict__ KH,
                                                 const ushort* __restrict__ Vt,
                                                 const ushort* __restrict__ Kp,
                                                 const ushort* __restrict__ Vpt,
                                                 float* __restrict__ out) {
  __shared__ alignas(16) unsigned Op[8][4][64][4];  // 32 KB packed O partials
  __shared__ float Ls[8][4][4][4];                  // 2 KB denom partials [w][tt][quad][r]
  const int idx = blockIdx.x;
  const int t = threadIdx.x;
  const int w = t >> 6, lane = t & 63;
  const int quad = lane >> 4, l15 = lane & 15;
  const int kperm1 = 8 * (l15 >> 2) + (l15 & 3);
  const f32x4 z = {0.f,0.f,0.f,0.f};

  BF8 ones;  // bf16 1.0 broadcast, B operand for row-sum MFMA
#pragma unroll
  for (int i2 = 0; i2 < 4; ++i2) ones.u32[i2] = 0x3F803F80u;

  if (idx < NFULL) {
    const int bh = (idx & 7) + 8 * ((idx >> 3) & 3);
    const int m = 31 - (idx >> 5);
    const int b = bh >> 3, h = bh & 7;
    const int q0 = 64 * m;

    BF8 qh[4];
#pragma unroll
    for (int tt = 0; tt < 4; ++tt)
      load8_bf(Q + ((size_t)(b * N_ + q0 + 16 * tt + l15) * H_ + h) * D_ + quad * 8,
               SCL2, qh[tt]);

    // per-lane base pointers (k2 = k1 + 4*D_ elements, 512B immediate)
    const ushort* KHl = KH + (size_t)bh * N_ * D_ + (size_t)kperm1 * D_ + quad * 8;
    const ushort* V0l = Vt + ((size_t)bh * D_ + l15) * N_ + quad * 8;
    const ushort* V1l = V0l + (size_t)16 * N_;

    const int nun = 2 * m;                       // shared unmasked chunks
    const int cb = (w * nun) >> 3;
    const int ce = ((w + 1) * nun) >> 3;
    const int nwu = ce - cb;

    f32x4 O0[4], O1[4], LS[4];
#pragma unroll
    for (int tt = 0; tt < 4; ++tt) { O0[tt] = z; O1[tt] = z; LS[tt] = z; }

    BF8 kA1, kA2, vA0, vA1, kB1, kB2, vB0, vB1;

    auto procU = [&](BF8& k1, BF8& k2, BF8& v0, BF8& v1) {
      __builtin_amdgcn_s_setprio(1);
#pragma unroll
      for (int tt = 0; tt < 4; ++tt) {
        f32x4 s1 = __builtin_amdgcn_mfma_f32_16x16x32_bf16(k1.b, qh[tt].b, z, 0, 0, 0);
        f32x4 s2 = __builtin_amdgcn_mfma_f32_16x16x32_bf16(k2.b, qh[tt].b, z, 0, 0, 0);
        float e0 = ex2(s1[0]), e1 = ex2(s1[1]), e2 = ex2(s1[2]), e3 = ex2(s1[3]);
        float e4 = ex2(s2[0]), e5 = ex2(s2[1]), e6 = ex2(s2[2]), e7 = ex2(s2[3]);
        BF8 p;
        p.u32[0] = pkbf(e0, e1); p.u32[1] = pkbf(e2, e3);
        p.u32[2] = pkbf(e4, e5); p.u32[3] = pkbf(e6, e7);
        O0[tt] = __builtin_amdgcn_mfma_f32_16x16x32_bf16(p.b, v0.b, O0[tt], 0, 0, 0);
        O1[tt] = __builtin_amdgcn_mfma_f32_16x16x32_bf16(p.b, v1.b, O1[tt], 0, 0, 0);
        LS[tt] = __builtin_amdgcn_mfma_f32_16x16x32_bf16(p.b, ones.b, LS[tt], 0, 0, 0);
      }
      __builtin_amdgcn_s_setprio(0);
    };
    // masked pair (tiles ta: thr=l15, ta+1: thr=16+l15); tiles tb,tb+1 unmasked opt
    auto procM = [&](BF8& k1, BF8& k2, BF8& v0, BF8& v1, int ta, bool doUnm) {
      __builtin_amdgcn_s_setprio(1);
#pragma unroll
      for (int d = 0; d < 2; ++d) {
        const int tt = ta + d;
        const int thr = d ? 16 + l15 : l15;
        f32x4 s1 = __builtin_amdgcn_mfma_f32_16x16x32_bf16(k1.b, qh[tt].b, z, 0, 0, 0);
        f32x4 s2 = __builtin_amdgcn_mfma_f32_16x16x32_bf16(k2.b, qh[tt].b, z, 0, 0, 0);
        float e[8];
#pragma unroll
        for (int j = 0; j < 8; ++j) {
          const float sv = (j < 4) ? s1[j] : s2[j - 4];
          e[j] = (8 * quad + j <= thr) ? ex2(sv) : 0.f;
        }
        BF8 p;
        p.u32[0] = pkbf(e[0], e[1]); p.u32[1] = pkbf(e[2], e[3]);
        p.u32[2] = pkbf(e[4], e[5]); p.u32[3] = pkbf(e[6], e[7]);
        O0[tt] = __builtin_amdgcn_mfma_f32_16x16x32_bf16(p.b, v0.b, O0[tt], 0, 0, 0);
        O1[tt] = __builtin_amdgcn_mfma_f32_16x16x32_bf16(p.b, v1.b, O1[tt], 0, 0, 0);
        LS[tt] = __builtin_amdgcn_mfma_f32_16x16x32_bf16(p.b, ones.b, LS[tt], 0, 0, 0);
      }
      if (doUnm) {
#pragma unroll
        for (int tt = 2; tt < 4; ++tt) {
          f32x4 s1 = __builtin_amdgcn_mfma_f32_16x16x32_bf16(k1.b, qh[tt].b, z, 0, 0, 0);
          f32x4 s2 = __builtin_amdgcn_mfma_f32_16x16x32_bf16(k2.b, qh[tt].b, z, 0, 0, 0);
          float e0 = ex2(s1[0]), e1 = ex2(s1[1]), e2 = ex2(s1[2]), e3 = ex2(s1[3]);
          float e4 = ex2(s2[0]), e5 = ex2(s2[1]), e6 = ex2(s2[2]), e7 = ex2(s2[3]);
          BF8 p;
          p.u32[0] = pkbf(e0, e1); p.u32[1] = pkbf(e2, e3);
          p.u32[2] = pkbf(e4, e5); p.u32[3] = pkbf(e6, e7);
          O0[tt] = __builtin_amdgcn_mfma_f32_16x16x32_bf16(p.b, v0.b, O0[tt], 0, 0, 0);
          O1[tt] = __builtin_amdgcn_mfma_f32_16x16x32_bf16(p.b, v1.b, O1[tt], 0, 0, 0);
          LS[tt] = __builtin_amdgcn_mfma_f32_16x16x32_bf16(p.b, ones.b, LS[tt], 0, 0, 0);
        }
      }
      __builtin_amdgcn_s_setprio(0);
    };

    // initial loads: chunks cb (A) and cb+1 (B); over-reads stay in mapped ws
    kA1.u4 = *reinterpret_cast<const uint4*>(KHl + (size_t)cb * CHK);
    kA2.u4 = *reinterpret_cast<const uint4*>(KHl + (size_t)cb * CHK + 4 * D_);
    vA0.u4 = *reinterpret_cast<const uint4*>(V0l + cb * 32);
    vA1.u4 = *reinterpret_cast<const uint4*>(V1l + cb * 32);
    kB1.u4 = *reinterpret_cast<const uint4*>(KHl + (size_t)(cb + 1) * CHK);
    kB2.u4 = *reinterpret_cast<const uint4*>(KHl + (size_t)(cb + 1) * CHK + 4 * D_);
    vB0.u4 = *reinterpret_cast<const uint4*>(V0l + (cb + 1) * 32);
    vB1.u4 = *reinterpret_cast<const uint4*>(V1l + (cb + 1) * 32);

    const ushort* pKA = KHl + (size_t)(cb + 2) * CHK;
    const ushort* pKB = KHl + (size_t)(cb + 3) * CHK;
    const ushort* pV0 = V0l + (cb + 2) * 32;
    const ushort* pV1 = V1l + (cb + 2) * 32;

    int i = 0;
    for (; i + 2 <= nwu; i += 2) {
      procU(kA1, kA2, vA0, vA1);
      kA1.u4 = *reinterpret_cast<const uint4*>(pKA);
      kA2.u4 = *reinterpret_cast<const uint4*>(pKA + 4 * D_);
      vA0.u4 = *reinterpret_cast<const uint4*>(pV0);
      vA1.u4 = *reinterpret_cast<const uint4*>(pV1);
      procU(kB1, kB2, vB0, vB1);
      kB1.u4 = *reinterpret_cast<const uint4*>(pKB);
      kB2.u4 = *reinterpret_cast<const uint4*>(pKB + 4 * D_);
      vB0.u4 = *reinterpret_cast<const uint4*>(pV0 + 32);
      vB1.u4 = *reinterpret_cast<const uint4*>(pV1 + 32);
      pKA += 2 * CHK; pKB += 2 * CHK; pV0 += 64; pV1 += 64;
    }
    if (i < nwu) {  // one unmasked left in A; wave7's boundary chunk is in B
      procU(kA1, kA2, vA0, vA1);
      if (w == 7) procM(kB1, kB2, vB0, vB1, 0, true);
    } else if (w == 7) {  // boundary chunk nun is in A
      procM(kA1, kA2, vA0, vA1, 0, true);
    }
    if (w == 6) {  // boundary chunk nun+1 (cold load): tiles 2,3 masked
      const int c2 = nun + 1;
      kB1.u4 = *reinterpret_cast<const uint4*>(KHl + (size_t)c2 * CHK);
      kB2.u4 = *reinterpret_cast<const uint4*>(KHl + (size_t)c2 * CHK + 4 * D_);
      vB0.u4 = *reinterpret_cast<const uint4*>(V0l + c2 * 32);
      vB1.u4 = *reinterpret_cast<const uint4*>(V1l + c2 * 32);
      procM(kB1, kB2, vB0, vB1, 2, false);
    }

    // --- combine: b128 bf16-packed O partials + broadcast f32 denom ---
#pragma unroll
    for (int tt = 0; tt < 4; ++tt) {
      uint4 pk;
      pk.x = pkbf(O0[tt][0], O0[tt][1]);
      pk.y = pkbf(O0[tt][2], O0[tt][3]);
      pk.z = pkbf(O1[tt][0], O1[tt][1]);
      pk.w = pkbf(O1[tt][2], O1[tt][3]);
      *reinterpret_cast<uint4*>(Op[w][tt][lane]) = pk;
    }
    if (l15 == 0) {
#pragma unroll
      for (int tt = 0; tt < 4; ++tt)
#pragma unroll
        for (int r = 0; r < 4; ++r) Ls[w][tt][quad][r] = LS[tt][r];
    }
    __syncthreads();
    {
      const int tt = w & 3;    // tile
      const int half = w >> 2; // output column half (A0 vs A1)
      float iv[4];
#pragma unroll
      for (int r = 0; r < 4; ++r) {
        const float l = ((Ls[0][tt][quad][r] + Ls[1][tt][quad][r]) +
                         (Ls[2][tt][quad][r] + Ls[3][tt][quad][r])) +
                        ((Ls[4][tt][quad][r] + Ls[5][tt][quad][r]) +
                         (Ls[6][tt][quad][r] + Ls[7][tt][quad][r]));
        iv[r] = __builtin_amdgcn_rcpf(l);
      }
      float A[4] = {0.f,0.f,0.f,0.f};
#pragma unroll
      for (int s = 0; s < 8; ++s) {
        const uint2 u = *reinterpret_cast<const uint2*>(&Op[s][tt][lane][half * 2]);
        A[0] += bflo(u.x); A[1] += bfhi(u.x);
        A[2] += bflo(u.y); A[3] += bfhi(u.y);
      }
#pragma unroll
      for (int r = 0; r < 4; ++r) {
        const int q = q0 + 16 * tt + quad * 4 + r;
        const size_t base = ((size_t)(b * N_ + q) * H_ + h) * D_;
        out[base + 16 * half + l15] = A[r] * iv[r];
      }
    }
  } else {
    // ---- Linformer part: 512 blocks, each covers 128 q rows (8 waves) ----
    const int j = idx - NFULL;
    const int bh = (j & 7) + 8 * ((j >> 3) & 3);
    const int b = bh >> 3, h = bh & 7;
    const int q0 = (j >> 5) * 128 + w * 16;
    float* olin = out + (size_t)B_ * N_ * H_ * D_;

    BF8 qh;
    load8_bf(Q + ((size_t)(b * N_ + q0 + l15) * H_ + h) * D_ + quad * 8, SCL2, qh);

    const int kperm2 = kperm1 + 4;
    const ushort* KpHb = Kp + (size_t)bh * KP_ * D_ + quad * 8;
    const ushort* Vp0 = Vpt + ((size_t)bh * D_ + l15) * KP_ + quad * 8;
    const ushort* Vp1 = Vp0 + (size_t)16 * KP_;

    // raw exp + packed raw P; denominator via ones-MFMA (C rows quad*4+r
    // align with output rows); normalization deferred to the 8 outputs.
    BF8 pg[8];
    f32x4 LSum = z;
    __builtin_amdgcn_s_setprio(1);
#pragma unroll
    for (int g = 0; g < 8; ++g) {
      const int kp0 = g * 32;
      BF8 a1, a2;
      a1.u4 = *reinterpret_cast<const uint4*>(KpHb + (size_t)(kp0 + kperm1) * D_);
      a2.u4 = *reinterpret_cast<const uint4*>(KpHb + (size_t)(kp0 + kperm2) * D_);
      f32x4 s1 = __builtin_amdgcn_mfma_f32_16x16x32_bf16(a1.b, qh.b, z, 0, 0, 0);
      f32x4 s2 = __builtin_amdgcn_mfma_f32_16x16x32_bf16(a2.b, qh.b, z, 0, 0, 0);
      const float e0 = ex2(s1[0]), e1 = ex2(s1[1]), e2 = ex2(s1[2]), e3 = ex2(s1[3]);
      const float e4 = ex2(s2[0]), e5 = ex2(s2[1]), e6 = ex2(s2[2]), e7 = ex2(s2[3]);
      pg[g].u32[0] = pkbf(e0, e1); pg[g].u32[1] = pkbf(e2, e3);
      pg[g].u32[2] = pkbf(e4, e5); pg[g].u32[3] = pkbf(e6, e7);
      LSum = __builtin_amdgcn_mfma_f32_16x16x32_bf16(pg[g].b, ones.b, LSum, 0, 0, 0);
    }

    f32x4 O0 = z, O1 = z;
#pragma unroll
    for (int g = 0; g < 8; ++g) {
      BF8 v0, v1;
      v0.u4 = *reinterpret_cast<const uint4*>(Vp0 + g * 32);
      v1.u4 = *reinterpret_cast<const uint4*>(Vp1 + g * 32);
      O0 = __builtin_amdgcn_mfma_f32_16x16x32_bf16(pg[g].b, v0.b, O0, 0, 0, 0);
      O1 = __builtin_amdgcn_mfma_f32_16x16x32_bf16(pg[g].b, v1.b, O1, 0, 0, 0);
    }
    __builtin_amdgcn_s_setprio(0);

#pragma unroll
    for (int r = 0; r < 4; ++r) {
      const float fr = __builtin_amdgcn_rcpf(LSum[r]);
      const int q = q0 + quad * 4 + r;
      const size_t base = ((size_t)(b * N_ + q) * H_ + h) * D_;
      olin[base + l15]      = O0[r] * fr;
      olin[base + 16 + l15] = O1[r] * fr;
    }
  }
}

// ---------------------------------------------------------------------------
extern "C" void kernel_launch(void* const* d_in, const int* in_sizes, int n_in,
                              void* d_out, int out_size, void* d_ws, size_t ws_size,
                              hipStream_t stream) {
  const float* Q = (const float*)d_in[0];
  const float* K = (const float*)d_in[1];
  const float* V = (const float*)d_in[2];
  const float* E = (const float*)d_in[3];
  const float* F = (const float*)d_in[4];
  float* out = (float*)d_out;

  // workspace layout (ushort elements), ~15 MB total
  ushort* KH  = (ushort*)d_ws;                        // [BH][N][D]  4 MB
  ushort* Kt  = KH + (size_t)BH_ * N_ * D_;           // [BH][D][N]  4 MB
  ushort* Vt  = Kt + (size_t)BH_ * N_ * D_;           // [BH][D][N]  4 MB
  ushort* Et  = Vt + (size_t)BH_ * N_ * D_;           // [KP][N]     1 MB
  ushort* Ft  = Et + (size_t)KP_ * N_;                // [KP][N]     1 MB
  ushort* Kp  = Ft + (size_t)KP_ * N_;                // [BH][KP][D] 0.5 MB
  ushort* Vpt = Kp + (size_t)BH_ * KP_ * D_;          // [BH][D][KP] 0.5 MB

  k_prep<<<dim3(1280), 256, 0, stream>>>(K, V, E, F, KH, Kt, Vt, Et, Ft);
  k_linproj<<<dim3(512), 512, 0, stream>>>(Et, Ft, Kt, Vt, Kp, Vpt);
  k_attn<<<dim3(NFULL + 512), 512, 0, stream>>>(Q, KH, Vt, Kp, Vpt, out);
}

// Round 6
// 148.516 us; speedup vs baseline: 1.0085x; 1.0085x over previous
//
#include <hip/hip_runtime.h>
#include <hip/hip_bf16.h>

// dsfa_former: (1) causal full attention + (2) Linformer attention.
// Inputs fp32, outputs fp32. Internal bf16 MFMA, exp2 softmax (no-max:
// scores bounded, softmax is scale-free in fp32).
// B=4, N=2048, H=8, d=32, kproj=256.
//
// Round-16: MERGED kernel. Round-5's 8-way split regressed (occupancy
// 34% yet slower => not occupancy-bound; cost = per-block fixed work +
// 2 scheduling generations). Revert causal path to round-3 (best, 43us),
// and fold the Linformer half into the causal blocks: after the causal
// combine, wave w runs Linformer for its own 16 rows reusing qh[w].
// Grid 2048->1024 blocks (4 waves/SIMD, single generation, every block
// resident from t=0); deletes 1024 launches + 1024x(Q fetch+convert).
// Round-14 retained: linproj 8-wave ping-pong, prep packed converts.
// Round-11 retained: raw v_exp_f32, ones-MFMA softmax denominator,
// b128 packed LDS combine + broadcast Ls, deferred 1/l normalization.
// Round-10 retained: quad-tile blocks, ping-pong prefetch, S^T trick.
//
// Fragment layouts (learn_hip m89/m91/m120):
//   C/D: per-lane row = quad*4 + reg, col = lane&15
//   A:   lane holds A[m = lane&15][k = quad*8 + j], j=0..7
//   B:   lane holds B[k = quad*8 + j][n = lane&15]

typedef __bf16 bf16x8 __attribute__((ext_vector_type(8)));
typedef __bf16 bf16x2 __attribute__((ext_vector_type(2)));
typedef float f32x4 __attribute__((ext_vector_type(4)));

union BF8 { uint4 u4; ushort us[8]; bf16x8 b; unsigned u32[4]; };

constexpr int B_ = 4, N_ = 2048, H_ = 8, D_ = 32, KP_ = 256, BH_ = 32;
constexpr float SCL2 = 0.25505654442633533f;  // (1/sqrt(32)) * log2(e)
constexpr int NFULL = 1024;                   // merged blocks
constexpr int CHK = 32 * D_;                  // K chunk stride (ushorts)

__device__ __forceinline__ ushort f2bf(float f) {
  unsigned u = __builtin_bit_cast(unsigned, f);
  return (ushort)((u + 0x7FFFu + ((u >> 16) & 1u)) >> 16);
}
// pack two floats -> bf16 pair (lo = first arg)
__device__ __forceinline__ unsigned pkbf(float f0, float f1) {
#if __has_builtin(__builtin_amdgcn_cvt_pk_bf16_f32)
  bf16x2 r = __builtin_amdgcn_cvt_pk_bf16_f32(f0, f1);
  return __builtin_bit_cast(unsigned, r);
#else
  unsigned u0 = __builtin_bit_cast(unsigned, f0) + 0x8000u;
  unsigned u1 = __builtin_bit_cast(unsigned, f1) + 0x8000u;
  return __builtin_amdgcn_perm(u1, u0, 0x07060302);  // [u1.hi : u0.hi]
#endif
}
__device__ __forceinline__ float bflo(unsigned u) {
  return __builtin_bit_cast(float, u << 16);
}
__device__ __forceinline__ float bfhi(unsigned u) {
  return __builtin_bit_cast(float, u & 0xFFFF0000u);
}
// raw v_exp_f32: scores bounded, no -inf fed in, denormal output flushes
// to 0 which is exactly what softmax wants.
__device__ __forceinline__ float ex2(float x) {
#if __has_builtin(__builtin_amdgcn_exp2f)
  return __builtin_amdgcn_exp2f(x);
#else
  return exp2f(x);
#endif
}

__device__ __forceinline__ void load8_bf(const float* __restrict__ p,
                                         float scale, BF8& hi) {
  float4 a = *reinterpret_cast<const float4*>(p);
  float4 b = *reinterpret_cast<const float4*>(p + 4);
  float x[8] = {a.x, a.y, a.z, a.w, b.x, b.y, b.z, b.w};
#pragma unroll
  for (int i = 0; i < 8; ++i) hi.us[i] = f2bf(x[i] * scale);
}

// ---------------------------------------------------------------------------
// Fused prep. Flat grid 1280 blocks of 256:
//   idx < 1024: K -> KH[bh][n][e] bf16, K -> Kt[bh][e][n], V -> Vt[bh][e][n]
//   idx >= 1024: E -> Et[KP][N] bf16 / F -> Ft (256 blocks)
// ---------------------------------------------------------------------------
__global__ __launch_bounds__(256) void k_prep(const float* __restrict__ K,
                                              const float* __restrict__ V,
                                              const float* __restrict__ E,
                                              const float* __restrict__ F,
                                              ushort* __restrict__ KH,
                                              ushort* __restrict__ Kt,
                                              ushort* __restrict__ Vt,
                                              ushort* __restrict__ Et,
                                              ushort* __restrict__ Ft) {
  __shared__ alignas(16) ushort S[4224];
  const int idx = blockIdx.x;
  const int t = threadIdx.x;
  if (idx < 1024) {
    ushort* Tk = S;            // [e][n_local] stride 66
    ushort* Tv = S + 2112;
    const int bh = idx >> 5, b = bh >> 3, h = bh & 7;
    const int n0 = (idx & 31) * 64;
    {
      const int row = t >> 2, e8 = (t & 3) * 8;
      const size_t gbase = ((size_t)(b * N_ + n0 + row) * H_ + h) * D_ + e8;
      float4 k0 = *reinterpret_cast<const float4*>(K + gbase);
      float4 k1 = *reinterpret_cast<const float4*>(K + gbase + 4);
      float4 v0 = *reinterpret_cast<const float4*>(V + gbase);
      float4 v1 = *reinterpret_cast<const float4*>(V + gbase + 4);
      float kk[8] = {k0.x,k0.y,k0.z,k0.w,k1.x,k1.y,k1.z,k1.w};
      float vv[8] = {v0.x,v0.y,v0.z,v0.w,v1.x,v1.y,v1.z,v1.w};
      BF8 xh, vh;
#pragma unroll
      for (int i = 0; i < 4; ++i) {
        xh.u32[i] = pkbf(kk[2 * i], kk[2 * i + 1]);
        vh.u32[i] = pkbf(vv[2 * i], vv[2 * i + 1]);
      }
#pragma unroll
      for (int i = 0; i < 8; ++i) {
        Tk[(e8 + i) * 66 + row] = xh.us[i];
        Tv[(e8 + i) * 66 + row] = vh.us[i];
      }
      *reinterpret_cast<uint4*>(KH + ((size_t)bh * N_ + n0 + row) * D_ + e8) = xh.u4;
    }
    __syncthreads();
    {
      const int e = t >> 3, n8 = (t & 7) * 8;
      BF8 xk, xv;
#pragma unroll
      for (int i = 0; i < 8; ++i) {
        xk.us[i] = Tk[e * 66 + n8 + i];
        xv.us[i] = Tv[e * 66 + n8 + i];
      }
      const size_t ob = ((size_t)bh * D_ + e) * N_ + n0 + n8;
      *reinterpret_cast<uint4*>(Kt + ob) = xk.u4;
      *reinterpret_cast<uint4*>(Vt + ob) = xv.u4;
    }
  } else {
    const int j = idx - 1024;
    const float* src = (j >> 7) ? F : E;
    ushort* dst = (j >> 7) ? Ft : Et;
    const int jj = j & 127;
    const int n0 = (jj & 31) * 64, kp0 = (jj >> 5) * 64;
    ushort* T = S;  // [kp_local][n_local] stride 66
    {
      const int n = t >> 2, c16 = (t & 3) * 16;
      const size_t gbase = (size_t)(n0 + n) * KP_ + kp0 + c16;
#pragma unroll
      for (int q = 0; q < 4; ++q) {
        float4 x = *reinterpret_cast<const float4*>(src + gbase + q * 4);
        const unsigned u01 = pkbf(x.x, x.y), u23 = pkbf(x.z, x.w);
        T[(c16 + q * 4 + 0) * 66 + n] = (ushort)u01;
        T[(c16 + q * 4 + 1) * 66 + n] = (ushort)(u01 >> 16);
        T[(c16 + q * 4 + 2) * 66 + n] = (ushort)u23;
        T[(c16 + q * 4 + 3) * 66 + n] = (ushort)(u23 >> 16);
      }
    }
    __syncthreads();
    {
      const int kp = t >> 2, n16 = (t & 3) * 16;
      BF8 x0, x1;
#pragma unroll
      for (int i = 0; i < 8; ++i) {
        x0.us[i] = T[kp * 66 + n16 + i];
        x1.us[i] = T[kp * 66 + n16 + 8 + i];
      }
      const size_t ob = (size_t)(kp0 + kp) * N_ + n0 + n16;
      *reinterpret_cast<uint4*>(dst + ob) = x0.u4;
      *reinterpret_cast<uint4*>(dst + ob + 8) = x1.u4;
    }
  }
}

// ---------------------------------------------------------------------------
// Kernel: Kp[bh][kp][e] (bf16) and Vpt[bh][e][kp]. Flat grid 512 blocks of
// 512 threads (8 waves, N/8 per wave), XCD-pinned bh, ping-pong prefetch,
// LDS combine over 8 partials.
// ---------------------------------------------------------------------------
__global__ __launch_bounds__(512) void k_linproj(const ushort* __restrict__ Et,
                                                 const ushort* __restrict__ Ft,
                                                 const ushort* __restrict__ Kt,
                                                 const ushort* __restrict__ Vt,
                                                 ushort* __restrict__ Kp,
                                                 ushort* __restrict__ Vpt) {
  __shared__ float L[8][64][16];  // 32 KB
  const int id = blockIdx.x;
  const int bh = (id & 7) + 8 * ((id >> 3) & 3);   // XCD pinning
  const int kp16 = (id >> 5) * 16;
  const int t = threadIdx.x;
  const int w = t >> 6, lane = t & 63, quad = lane >> 4, l15 = lane & 15;
  const int nbase = w * (N_ / 8);                  // 256 per wave

  const ushort* eA = Et + (size_t)(kp16 + l15) * N_ + nbase + quad * 8;
  const ushort* fA = Ft + (size_t)(kp16 + l15) * N_ + nbase + quad * 8;
  const ushort* kB0 = Kt + ((size_t)bh * D_ + l15) * N_ + nbase + quad * 8;
  const ushort* kB1 = kB0 + (size_t)16 * N_;
  const ushort* vB0 = Vt + ((size_t)bh * D_ + l15) * N_ + nbase + quad * 8;
  const ushort* vB1 = vB0 + (size_t)16 * N_;

  f32x4 accK0 = {0.f,0.f,0.f,0.f}, accK1 = {0.f,0.f,0.f,0.f};
  f32x4 accV0 = {0.f,0.f,0.f,0.f}, accV1 = {0.f,0.f,0.f,0.f};

  BF8 e0, f0, k00, k10, v00, v10;   // buffer A
  BF8 e1, f1, k01, k11, v01, v11;   // buffer B

#define LPLD(E, F, K0, K1, V0, V1, NO)                                \
  do {                                                                \
    (E).u4 = *reinterpret_cast<const uint4*>(eA + (NO));              \
    (F).u4 = *reinterpret_cast<const uint4*>(fA + (NO));              \
    (K0).u4 = *reinterpret_cast<const uint4*>(kB0 + (NO));            \
    (K1).u4 = *reinterpret_cast<const uint4*>(kB1 + (NO));            \
    (V0).u4 = *reinterpret_cast<const uint4*>(vB0 + (NO));            \
    (V1).u4 = *reinterpret_cast<const uint4*>(vB1 + (NO));            \
  } while (0)
#define LPMM(E, F, K0, K1, V0, V1)                                            \
  do {                                                                        \
    accK0 = __builtin_amdgcn_mfma_f32_16x16x32_bf16((E).b, (K0).b, accK0, 0, 0, 0); \
    accK1 = __builtin_amdgcn_mfma_f32_16x16x32_bf16((E).b, (K1).b, accK1, 0, 0, 0); \
    accV0 = __builtin_amdgcn_mfma_f32_16x16x32_bf16((F).b, (V0).b, accV0, 0, 0, 0); \
    accV1 = __builtin_amdgcn_mfma_f32_16x16x32_bf16((F).b, (V1).b, accV1, 0, 0, 0); \
  } while (0)

  LPLD(e0, f0, k00, k10, v00, v10, 0);
  LPLD(e1, f1, k01, k11, v01, v11, 32);
#pragma unroll
  for (int p = 0; p < 3; ++p) {
    LPMM(e0, f0, k00, k10, v00, v10);
    LPLD(e0, f0, k00, k10, v00, v10, (2 * p + 2) * 32);
    LPMM(e1, f1, k01, k11, v01, v11);
    LPLD(e1, f1, k01, k11, v01, v11, (2 * p + 3) * 32);
  }
  LPMM(e0, f0, k00, k10, v00, v10);
  LPMM(e1, f1, k01, k11, v01, v11);
#undef LPLD
#undef LPMM

#pragma unroll
  for (int r = 0; r < 4; ++r) {
    L[w][lane][r]      = accK0[r];
    L[w][lane][4 + r]  = accK1[r];
    L[w][lane][8 + r]  = accV0[r];
    L[w][lane][12 + r] = accV1[r];
  }
  __syncthreads();
  if (w < 4) {
#pragma unroll
    for (int r = 0; r < 4; ++r) {
      const float v = ((L[0][lane][w * 4 + r] + L[1][lane][w * 4 + r]) +
                       (L[2][lane][w * 4 + r] + L[3][lane][w * 4 + r])) +
                      ((L[4][lane][w * 4 + r] + L[5][lane][w * 4 + r]) +
                       (L[6][lane][w * 4 + r] + L[7][lane][w * 4 + r]));
      const int kp = kp16 + quad * 4 + r;
      if (w == 0)      Kp[((size_t)bh * KP_ + kp) * D_ + l15]       = f2bf(v);
      else if (w == 1) Kp[((size_t)bh * KP_ + kp) * D_ + 16 + l15]  = f2bf(v);
      else if (w == 2) Vpt[((size_t)bh * D_ + l15) * KP_ + kp]      = f2bf(v);
      else             Vpt[((size_t)bh * D_ + 16 + l15) * KP_ + kp] = f2bf(v);
    }
  }
}

// ---------------------------------------------------------------------------
// Merged attention. Grid 1024 blocks of 256 (4 waves):
//   Causal full attention, quad-tile block (q rows [64m,64m+64)).
//   bh = (idx&7)+8*((idx>>3)&3) (XCD pinning), m = 31-(idx>>5) (LPT).
//   Waves k-split chunks [0,2m); wave 3 takes boundary chunk 2m, wave 2
//   takes chunk 2m+1. b128 bf16-packed LDS combine + broadcast Ls (17 KB).
//   Then: Linformer for the SAME 64 rows, wave w = tile w, reusing qh[w].
// ---------------------------------------------------------------------------
__global__ __launch_bounds__(256, 4) void k_attn(const float* __restrict__ Q,
                                                 const ushort* __restrict__ KH,
                                                 const ushort* __restrict__ Vt,
                                                 const ushort* __restrict__ Kp,
                                                 const ushort* __restrict__ Vpt,
                                                 float* __restrict__ out) {
  __shared__ alignas(16) unsigned Op[4][4][64][4];  // 16 KB packed O partials
  __shared__ float Ls[4][4][4][4];                  // 1 KB denom partials [w][tt][quad][r]
  const int idx = blockIdx.x;
  const int t = threadIdx.x;
  const int w = t >> 6, lane = t & 63;
  const int quad = lane >> 4, l15 = lane & 15;
  const int kperm1 = 8 * (l15 >> 2) + (l15 & 3);
  const f32x4 z = {0.f,0.f,0.f,0.f};

  BF8 ones;  // bf16 1.0 broadcast, B operand for row-sum MFMA
#pragma unroll
  for (int i2 = 0; i2 < 4; ++i2) ones.u32[i2] = 0x3F803F80u;

  const int bh = (idx & 7) + 8 * ((idx >> 3) & 3);
  const int m = 31 - (idx >> 5);
  const int b = bh >> 3, h = bh & 7;
  const int q0 = 64 * m;

  BF8 qh[4];
#pragma unroll
  for (int tt = 0; tt < 4; ++tt)
    load8_bf(Q + ((size_t)(b * N_ + q0 + 16 * tt + l15) * H_ + h) * D_ + quad * 8,
             SCL2, qh[tt]);

  {
    // per-lane base pointers (k2 = k1 + 4*D_ elements, 512B immediate)
    const ushort* KHl = KH + (size_t)bh * N_ * D_ + (size_t)kperm1 * D_ + quad * 8;
    const ushort* V0l = Vt + ((size_t)bh * D_ + l15) * N_ + quad * 8;
    const ushort* V1l = V0l + (size_t)16 * N_;

    const int nun = 2 * m;                       // shared unmasked chunks
    const int cb = (w * nun) >> 2;
    const int ce = ((w + 1) * nun) >> 2;
    const int nwu = ce - cb;

    f32x4 O0[4], O1[4], LS[4];
#pragma unroll
    for (int tt = 0; tt < 4; ++tt) { O0[tt] = z; O1[tt] = z; LS[tt] = z; }

    BF8 kA1, kA2, vA0, vA1, kB1, kB2, vB0, vB1;

    auto procU = [&](BF8& k1, BF8& k2, BF8& v0, BF8& v1) {
      __builtin_amdgcn_s_setprio(1);
#pragma unroll
      for (int tt = 0; tt < 4; ++tt) {
        f32x4 s1 = __builtin_amdgcn_mfma_f32_16x16x32_bf16(k1.b, qh[tt].b, z, 0, 0, 0);
        f32x4 s2 = __builtin_amdgcn_mfma_f32_16x16x32_bf16(k2.b, qh[tt].b, z, 0, 0, 0);
        float e0 = ex2(s1[0]), e1 = ex2(s1[1]), e2 = ex2(s1[2]), e3 = ex2(s1[3]);
        float e4 = ex2(s2[0]), e5 = ex2(s2[1]), e6 = ex2(s2[2]), e7 = ex2(s2[3]);
        BF8 p;
        p.u32[0] = pkbf(e0, e1); p.u32[1] = pkbf(e2, e3);
        p.u32[2] = pkbf(e4, e5); p.u32[3] = pkbf(e6, e7);
        O0[tt] = __builtin_amdgcn_mfma_f32_16x16x32_bf16(p.b, v0.b, O0[tt], 0, 0, 0);
        O1[tt] = __builtin_amdgcn_mfma_f32_16x16x32_bf16(p.b, v1.b, O1[tt], 0, 0, 0);
        LS[tt] = __builtin_amdgcn_mfma_f32_16x16x32_bf16(p.b, ones.b, LS[tt], 0, 0, 0);
      }
      __builtin_amdgcn_s_setprio(0);
    };
    // masked pair (tiles ta: thr=l15, ta+1: thr=16+l15); tiles tb,tb+1 unmasked opt
    auto procM = [&](BF8& k1, BF8& k2, BF8& v0, BF8& v1, int ta, bool doUnm) {
      __builtin_amdgcn_s_setprio(1);
#pragma unroll
      for (int d = 0; d < 2; ++d) {
        const int tt = ta + d;
        const int thr = d ? 16 + l15 : l15;
        f32x4 s1 = __builtin_amdgcn_mfma_f32_16x16x32_bf16(k1.b, qh[tt].b, z, 0, 0, 0);
        f32x4 s2 = __builtin_amdgcn_mfma_f32_16x16x32_bf16(k2.b, qh[tt].b, z, 0, 0, 0);
        float e[8];
#pragma unroll
        for (int j = 0; j < 8; ++j) {
          const float sv = (j < 4) ? s1[j] : s2[j - 4];
          e[j] = (8 * quad + j <= thr) ? ex2(sv) : 0.f;
        }
        BF8 p;
        p.u32[0] = pkbf(e[0], e[1]); p.u32[1] = pkbf(e[2], e[3]);
        p.u32[2] = pkbf(e[4], e[5]); p.u32[3] = pkbf(e[6], e[7]);
        O0[tt] = __builtin_amdgcn_mfma_f32_16x16x32_bf16(p.b, v0.b, O0[tt], 0, 0, 0);
        O1[tt] = __builtin_amdgcn_mfma_f32_16x16x32_bf16(p.b, v1.b, O1[tt], 0, 0, 0);
        LS[tt] = __builtin_amdgcn_mfma_f32_16x16x32_bf16(p.b, ones.b, LS[tt], 0, 0, 0);
      }
      if (doUnm) {
#pragma unroll
        for (int tt = 2; tt < 4; ++tt) {
          f32x4 s1 = __builtin_amdgcn_mfma_f32_16x16x32_bf16(k1.b, qh[tt].b, z, 0, 0, 0);
          f32x4 s2 = __builtin_amdgcn_mfma_f32_16x16x32_bf16(k2.b, qh[tt].b, z, 0, 0, 0);
          float e0 = ex2(s1[0]), e1 = ex2(s1[1]), e2 = ex2(s1[2]), e3 = ex2(s1[3]);
          float e4 = ex2(s2[0]), e5 = ex2(s2[1]), e6 = ex2(s2[2]), e7 = ex2(s2[3]);
          BF8 p;
          p.u32[0] = pkbf(e0, e1); p.u32[1] = pkbf(e2, e3);
          p.u32[2] = pkbf(e4, e5); p.u32[3] = pkbf(e6, e7);
          O0[tt] = __builtin_amdgcn_mfma_f32_16x16x32_bf16(p.b, v0.b, O0[tt], 0, 0, 0);
          O1[tt] = __builtin_amdgcn_mfma_f32_16x16x32_bf16(p.b, v1.b, O1[tt], 0, 0, 0);
          LS[tt] = __builtin_amdgcn_mfma_f32_16x16x32_bf16(p.b, ones.b, LS[tt], 0, 0, 0);
        }
      }
      __builtin_amdgcn_s_setprio(0);
    };

    // initial loads: chunks cb (A) and cb+1 (B); over-reads stay in mapped ws
    kA1.u4 = *reinterpret_cast<const uint4*>(KHl + (size_t)cb * CHK);
    kA2.u4 = *reinterpret_cast<const uint4*>(KHl + (size_t)cb * CHK + 4 * D_);
    vA0.u4 = *reinterpret_cast<const uint4*>(V0l + cb * 32);
    vA1.u4 = *reinterpret_cast<const uint4*>(V1l + cb * 32);
    kB1.u4 = *reinterpret_cast<const uint4*>(KHl + (size_t)(cb + 1) * CHK);
    kB2.u4 = *reinterpret_cast<const uint4*>(KHl + (size_t)(cb + 1) * CHK + 4 * D_);
    vB0.u4 = *reinterpret_cast<const uint4*>(V0l + (cb + 1) * 32);
    vB1.u4 = *reinterpret_cast<const uint4*>(V1l + (cb + 1) * 32);

    const ushort* pKA = KHl + (size_t)(cb + 2) * CHK;
    const ushort* pKB = KHl + (size_t)(cb + 3) * CHK;
    const ushort* pV0 = V0l + (cb + 2) * 32;
    const ushort* pV1 = V1l + (cb + 2) * 32;

    int i = 0;
    for (; i + 2 <= nwu; i += 2) {
      procU(kA1, kA2, vA0, vA1);
      kA1.u4 = *reinterpret_cast<const uint4*>(pKA);
      kA2.u4 = *reinterpret_cast<const uint4*>(pKA + 4 * D_);
      vA0.u4 = *reinterpret_cast<const uint4*>(pV0);
      vA1.u4 = *reinterpret_cast<const uint4*>(pV1);
      procU(kB1, kB2, vB0, vB1);
      kB1.u4 = *reinterpret_cast<const uint4*>(pKB);
      kB2.u4 = *reinterpret_cast<const uint4*>(pKB + 4 * D_);
      vB0.u4 = *reinterpret_cast<const uint4*>(pV0 + 32);
      vB1.u4 = *reinterpret_cast<const uint4*>(pV1 + 32);
      pKA += 2 * CHK; pKB += 2 * CHK; pV0 += 64; pV1 += 64;
    }
    if (i < nwu) {  // one unmasked left in A; wave3's boundary chunk is in B
      procU(kA1, kA2, vA0, vA1);
      if (w == 3) procM(kB1, kB2, vB0, vB1, 0, true);
    } else if (w == 3) {  // boundary chunk nun is in A
      procM(kA1, kA2, vA0, vA1, 0, true);
    }
    if (w == 2) {  // boundary chunk nun+1 (cold load): tiles 2,3 masked
      const int c2 = nun + 1;
      kB1.u4 = *reinterpret_cast<const uint4*>(KHl + (size_t)c2 * CHK);
      kB2.u4 = *reinterpret_cast<const uint4*>(KHl + (size_t)c2 * CHK + 4 * D_);
      vB0.u4 = *reinterpret_cast<const uint4*>(V0l + c2 * 32);
      vB1.u4 = *reinterpret_cast<const uint4*>(V1l + c2 * 32);
      procM(kB1, kB2, vB0, vB1, 2, false);
    }

    // --- combine: b128 bf16-packed O partials + broadcast f32 denom ---
#pragma unroll
    for (int tt = 0; tt < 4; ++tt) {
      uint4 pk;
      pk.x = pkbf(O0[tt][0], O0[tt][1]);
      pk.y = pkbf(O0[tt][2], O0[tt][3]);
      pk.z = pkbf(O1[tt][0], O1[tt][1]);
      pk.w = pkbf(O1[tt][2], O1[tt][3]);
      *reinterpret_cast<uint4*>(Op[w][tt][lane]) = pk;
    }
    if (l15 == 0) {
#pragma unroll
      for (int tt = 0; tt < 4; ++tt)
#pragma unroll
        for (int r = 0; r < 4; ++r) Ls[w][tt][quad][r] = LS[tt][r];
    }
    __syncthreads();
    {
      const int tt = w;  // wave w writes tile w
      float iv[4];
#pragma unroll
      for (int r = 0; r < 4; ++r) {
        const float l = Ls[0][tt][quad][r] + Ls[1][tt][quad][r] +
                        Ls[2][tt][quad][r] + Ls[3][tt][quad][r];
        iv[r] = __builtin_amdgcn_rcpf(l);
      }
      float A0[4] = {0.f,0.f,0.f,0.f}, A1[4] = {0.f,0.f,0.f,0.f};
#pragma unroll
      for (int s = 0; s < 4; ++s) {
        const uint4 u = *reinterpret_cast<const uint4*>(Op[s][tt][lane]);
        A0[0] += bflo(u.x); A0[1] += bfhi(u.x);
        A0[2] += bflo(u.y); A0[3] += bfhi(u.y);
        A1[0] += bflo(u.z); A1[1] += bfhi(u.z);
        A1[2] += bflo(u.w); A1[3] += bfhi(u.w);
      }
#pragma unroll
      for (int r = 0; r < 4; ++r) {
        const int q = q0 + 16 * tt + quad * 4 + r;
        const size_t base = ((size_t)(b * N_ + q) * H_ + h) * D_;
        out[base + l15]      = A0[r] * iv[r];
        out[base + 16 + l15] = A1[r] * iv[r];
      }
    }
  }

  // ---- Linformer for this block's rows: wave w = tile w, reuse qh[w] ----
  {
    float* olin = out + (size_t)B_ * N_ * H_ * D_;
    const int q0l = q0 + 16 * w;

    const int kperm2 = kperm1 + 4;
    const ushort* KpHb = Kp + (size_t)bh * KP_ * D_ + quad * 8;
    const ushort* Vp0 = Vpt + ((size_t)bh * D_ + l15) * KP_ + quad * 8;
    const ushort* Vp1 = Vp0 + (size_t)16 * KP_;

    // raw exp + packed raw P; denominator via ones-MFMA (C rows quad*4+r
    // align with output rows); normalization deferred to the 8 outputs.
    BF8 pg[8];
    f32x4 LSum = z;
    __builtin_amdgcn_s_setprio(1);
#pragma unroll
    for (int g = 0; g < 8; ++g) {
      const int kp0 = g * 32;
      BF8 a1, a2;
      a1.u4 = *reinterpret_cast<const uint4*>(KpHb + (size_t)(kp0 + kperm1) * D_);
      a2.u4 = *reinterpret_cast<const uint4*>(KpHb + (size_t)(kp0 + kperm2) * D_);
      f32x4 s1 = __builtin_amdgcn_mfma_f32_16x16x32_bf16(a1.b, qh[w].b, z, 0, 0, 0);
      f32x4 s2 = __builtin_amdgcn_mfma_f32_16x16x32_bf16(a2.b, qh[w].b, z, 0, 0, 0);
      const float e0 = ex2(s1[0]), e1 = ex2(s1[1]), e2 = ex2(s1[2]), e3 = ex2(s1[3]);
      const float e4 = ex2(s2[0]), e5 = ex2(s2[1]), e6 = ex2(s2[2]), e7 = ex2(s2[3]);
      pg[g].u32[0] = pkbf(e0, e1); pg[g].u32[1] = pkbf(e2, e3);
      pg[g].u32[2] = pkbf(e4, e5); pg[g].u32[3] = pkbf(e6, e7);
      LSum = __builtin_amdgcn_mfma_f32_16x16x32_bf16(pg[g].b, ones.b, LSum, 0, 0, 0);
    }

    f32x4 O0 = z, O1 = z;
#pragma unroll
    for (int g = 0; g < 8; ++g) {
      BF8 v0, v1;
      v0.u4 = *reinterpret_cast<const uint4*>(Vp0 + g * 32);
      v1.u4 = *reinterpret_cast<const uint4*>(Vp1 + g * 32);
      O0 = __builtin_amdgcn_mfma_f32_16x16x32_bf16(pg[g].b, v0.b, O0, 0, 0, 0);
      O1 = __builtin_amdgcn_mfma_f32_16x16x32_bf16(pg[g].b, v1.b, O1, 0, 0, 0);
    }
    __builtin_amdgcn_s_setprio(0);

#pragma unroll
    for (int r = 0; r < 4; ++r) {
      const float fr = __builtin_amdgcn_rcpf(LSum[r]);
      const int q = q0l + quad * 4 + r;
      const size_t base = ((size_t)(b * N_ + q) * H_ + h) * D_;
      olin[base + l15]      = O0[r] * fr;
      olin[base + 16 + l15] = O1[r] * fr;
    }
  }
}

// ---------------------------------------------------------------------------
extern "C" void kernel_launch(void* const* d_in, const int* in_sizes, int n_in,
                              void* d_out, int out_size, void* d_ws, size_t ws_size,
                              hipStream_t stream) {
  const float* Q = (const float*)d_in[0];
  const float* K = (const float*)d_in[1];
  const float* V = (const float*)d_in[2];
  const float* E = (const float*)d_in[3];
  const float* F = (const float*)d_in[4];
  float* out = (float*)d_out;

  // workspace layout (ushort elements), ~15 MB total
  ushort* KH  = (ushort*)d_ws;                        // [BH][N][D]  4 MB
  ushort* Kt  = KH + (size_t)BH_ * N_ * D_;           // [BH][D][N]  4 MB
  ushort* Vt  = Kt + (size_t)BH_ * N_ * D_;           // [BH][D][N]  4 MB
  ushort* Et  = Vt + (size_t)BH_ * N_ * D_;           // [KP][N]     1 MB
  ushort* Ft  = Et + (size_t)KP_ * N_;                // [KP][N]     1 MB
  ushort* Kp  = Ft + (size_t)KP_ * N_;                // [BH][KP][D] 0.5 MB
  ushort* Vpt = Kp + (size_t)BH_ * KP_ * D_;          // [BH][D][KP] 0.5 MB

  k_prep<<<dim3(1280), 256, 0, stream>>>(K, V, E, F, KH, Kt, Vt, Et, Ft);
  k_linproj<<<dim3(512), 512, 0, stream>>>(Et, Ft, Kt, Vt, Kp, Vpt);
  k_attn<<<dim3(NFULL), 256, 0, stream>>>(Q, KH, Vt, Kp, Vpt, out);
}

// Round 7
// 125.054 us; speedup vs baseline: 1.1978x; 1.1876x over previous
//
#include <hip/hip_runtime.h>
#include <hip/hip_bf16.h>

// dsfa_former: (1) causal full attention + (2) Linformer attention.
// Inputs fp32, outputs fp32. Internal bf16 MFMA, exp2 softmax (no-max:
// scores bounded, softmax is scale-free in fp32).
// B=4, N=2048, H=8, d=32, kproj=256.
//
// Round-17: COALESCED OPERAND LAYOUTS. Rounds 5/6 regressed via scratch
// spills (WRITE_SIZE 16.4->36.9MB); revert to round-3 structure (best,
// 142us). New theory for attn's 43us-with-idle-pipes: V loads are 16-way
// gathers (lane e=l15 -> 16 rows at 4KB stride per wave-load) vs KH's
// permuted-packed contiguous 2KB. Fix: chunk-tile all operands so every
// wave-load is one contiguous 2KB burst:
//   VC[bh][c][e][32k], KC same, EC/FC[c][kp][32k], VPC[bh][g][e][32k].
// Addressing-only change; k_attn otherwise byte-identical to round-3.
// Round-14 retained: linproj 8-wave ping-pong, prep packed converts.
// Round-11 retained: raw v_exp_f32, ones-MFMA softmax denominator,
// b128 packed LDS combine + broadcast Ls, deferred 1/l normalization.
// Round-10 retained: quad-tile blocks, ping-pong prefetch, S^T trick.
//
// Fragment layouts (learn_hip m89/m91/m120):
//   C/D: per-lane row = quad*4 + reg, col = lane&15
//   A:   lane holds A[m = lane&15][k = quad*8 + j], j=0..7
//   B:   lane holds B[k = quad*8 + j][n = lane&15]

typedef __bf16 bf16x8 __attribute__((ext_vector_type(8)));
typedef __bf16 bf16x2 __attribute__((ext_vector_type(2)));
typedef float f32x4 __attribute__((ext_vector_type(4)));

union BF8 { uint4 u4; ushort us[8]; bf16x8 b; unsigned u32[4]; };

constexpr int B_ = 4, N_ = 2048, H_ = 8, D_ = 32, KP_ = 256, BH_ = 32;
constexpr float SCL2 = 0.25505654442633533f;  // (1/sqrt(32)) * log2(e)
constexpr int NFULL = 1024;                   // causal blocks
constexpr int CHK = 32 * D_;                  // chunk stride (ushorts) = 1024

__device__ __forceinline__ ushort f2bf(float f) {
  unsigned u = __builtin_bit_cast(unsigned, f);
  return (ushort)((u + 0x7FFFu + ((u >> 16) & 1u)) >> 16);
}
// pack two floats -> bf16 pair (lo = first arg)
__device__ __forceinline__ unsigned pkbf(float f0, float f1) {
#if __has_builtin(__builtin_amdgcn_cvt_pk_bf16_f32)
  bf16x2 r = __builtin_amdgcn_cvt_pk_bf16_f32(f0, f1);
  return __builtin_bit_cast(unsigned, r);
#else
  unsigned u0 = __builtin_bit_cast(unsigned, f0) + 0x8000u;
  unsigned u1 = __builtin_bit_cast(unsigned, f1) + 0x8000u;
  return __builtin_amdgcn_perm(u1, u0, 0x07060302);  // [u1.hi : u0.hi]
#endif
}
__device__ __forceinline__ float bflo(unsigned u) {
  return __builtin_bit_cast(float, u << 16);
}
__device__ __forceinline__ float bfhi(unsigned u) {
  return __builtin_bit_cast(float, u & 0xFFFF0000u);
}
// raw v_exp_f32: scores bounded, no -inf fed in, denormal output flushes
// to 0 which is exactly what softmax wants.
__device__ __forceinline__ float ex2(float x) {
#if __has_builtin(__builtin_amdgcn_exp2f)
  return __builtin_amdgcn_exp2f(x);
#else
  return exp2f(x);
#endif
}

__device__ __forceinline__ void load8_bf(const float* __restrict__ p,
                                         float scale, BF8& hi) {
  float4 a = *reinterpret_cast<const float4*>(p);
  float4 b = *reinterpret_cast<const float4*>(p + 4);
  float x[8] = {a.x, a.y, a.z, a.w, b.x, b.y, b.z, b.w};
#pragma unroll
  for (int i = 0; i < 8; ++i) hi.us[i] = f2bf(x[i] * scale);
}

// ---------------------------------------------------------------------------
// Fused prep. Flat grid 1280 blocks of 256:
//   idx < 1024: K -> KH[bh][n][e] bf16 (permuted-packed),
//               K -> KC[bh][c][e][32k], V -> VC[bh][c][e][32k]
//   idx >= 1024: E -> EC[c][kp][32k] bf16 / F -> FC (256 blocks)
// ---------------------------------------------------------------------------
__global__ __launch_bounds__(256) void k_prep(const float* __restrict__ K,
                                              const float* __restrict__ V,
                                              const float* __restrict__ E,
                                              const float* __restrict__ F,
                                              ushort* __restrict__ KH,
                                              ushort* __restrict__ Kt,
                                              ushort* __restrict__ Vt,
                                              ushort* __restrict__ Et,
                                              ushort* __restrict__ Ft) {
  __shared__ alignas(16) ushort S[4224];
  const int idx = blockIdx.x;
  const int t = threadIdx.x;
  if (idx < 1024) {
    ushort* Tk = S;            // [e][n_local] stride 66
    ushort* Tv = S + 2112;
    const int bh = idx >> 5, b = bh >> 3, h = bh & 7;
    const int n0 = (idx & 31) * 64;
    {
      const int row = t >> 2, e8 = (t & 3) * 8;
      const size_t gbase = ((size_t)(b * N_ + n0 + row) * H_ + h) * D_ + e8;
      float4 k0 = *reinterpret_cast<const float4*>(K + gbase);
      float4 k1 = *reinterpret_cast<const float4*>(K + gbase + 4);
      float4 v0 = *reinterpret_cast<const float4*>(V + gbase);
      float4 v1 = *reinterpret_cast<const float4*>(V + gbase + 4);
      float kk[8] = {k0.x,k0.y,k0.z,k0.w,k1.x,k1.y,k1.z,k1.w};
      float vv[8] = {v0.x,v0.y,v0.z,v0.w,v1.x,v1.y,v1.z,v1.w};
      BF8 xh, vh;
#pragma unroll
      for (int i = 0; i < 4; ++i) {
        xh.u32[i] = pkbf(kk[2 * i], kk[2 * i + 1]);
        vh.u32[i] = pkbf(vv[2 * i], vv[2 * i + 1]);
      }
#pragma unroll
      for (int i = 0; i < 8; ++i) {
        Tk[(e8 + i) * 66 + row] = xh.us[i];
        Tv[(e8 + i) * 66 + row] = vh.us[i];
      }
      *reinterpret_cast<uint4*>(KH + ((size_t)bh * N_ + n0 + row) * D_ + e8) = xh.u4;
    }
    __syncthreads();
    {
      const int e = t >> 3, n8 = (t & 7) * 8;
      BF8 xk, xv;
#pragma unroll
      for (int i = 0; i < 8; ++i) {
        xk.us[i] = Tk[e * 66 + n8 + i];
        xv.us[i] = Tv[e * 66 + n8 + i];
      }
      // chunk-tiled: [bh][c][e][32k]
      const int c = (n0 + n8) >> 5, k = n8 & 31;
      const size_t ob = (((size_t)bh * 64 + c) * 32 + e) * 32 + k;
      *reinterpret_cast<uint4*>(Kt + ob) = xk.u4;
      *reinterpret_cast<uint4*>(Vt + ob) = xv.u4;
    }
  } else {
    const int j = idx - 1024;
    const float* src = (j >> 7) ? F : E;
    ushort* dst = (j >> 7) ? Ft : Et;
    const int jj = j & 127;
    const int n0 = (jj & 31) * 64, kp0 = (jj >> 5) * 64;
    ushort* T = S;  // [kp_local][n_local] stride 66
    {
      const int n = t >> 2, c16 = (t & 3) * 16;
      const size_t gbase = (size_t)(n0 + n) * KP_ + kp0 + c16;
#pragma unroll
      for (int q = 0; q < 4; ++q) {
        float4 x = *reinterpret_cast<const float4*>(src + gbase + q * 4);
        const unsigned u01 = pkbf(x.x, x.y), u23 = pkbf(x.z, x.w);
        T[(c16 + q * 4 + 0) * 66 + n] = (ushort)u01;
        T[(c16 + q * 4 + 1) * 66 + n] = (ushort)(u01 >> 16);
        T[(c16 + q * 4 + 2) * 66 + n] = (ushort)u23;
        T[(c16 + q * 4 + 3) * 66 + n] = (ushort)(u23 >> 16);
      }
    }
    __syncthreads();
    {
      const int kp = t >> 2, n16 = (t & 3) * 16;
      BF8 x0, x1;
#pragma unroll
      for (int i = 0; i < 8; ++i) {
        x0.us[i] = T[kp * 66 + n16 + i];
        x1.us[i] = T[kp * 66 + n16 + 8 + i];
      }
      // chunk-tiled: [c][kp][32k]
      const int c = (n0 + n16) >> 5, k = n16 & 31;
      const size_t ob = ((size_t)c * KP_ + kp0 + kp) * 32 + k;
      *reinterpret_cast<uint4*>(dst + ob) = x0.u4;
      *reinterpret_cast<uint4*>(dst + ob + 8) = x1.u4;
    }
  }
}

// ---------------------------------------------------------------------------
// Kernel: Kp[bh][kp][e] (bf16) and VPC[bh][g][e][32k]. Flat grid 512 blocks
// of 512 threads (8 waves, N/8 per wave), XCD-pinned bh, ping-pong prefetch,
// LDS combine over 8 partials. All global reads contiguous 2KB per wave-load.
// ---------------------------------------------------------------------------
__global__ __launch_bounds__(512) void k_linproj(const ushort* __restrict__ Et,
                                                 const ushort* __restrict__ Ft,
                                                 const ushort* __restrict__ Kt,
                                                 const ushort* __restrict__ Vt,
                                                 ushort* __restrict__ Kp,
                                                 ushort* __restrict__ Vpt) {
  __shared__ float L[8][64][16];  // 32 KB
  const int id = blockIdx.x;
  const int bh = (id & 7) + 8 * ((id >> 3) & 3);   // XCD pinning
  const int kp16 = (id >> 5) * 16;
  const int t = threadIdx.x;
  const int w = t >> 6, lane = t & 63, quad = lane >> 4, l15 = lane & 15;
  const int cbase = w * 8;                          // 8 chunks of 32 per wave

  // EC/FC: (c*KP + kp)*32 + k ; KC/VC: ((bh*64 + c)*32 + e)*32 + k
  const ushort* eA = Et + ((size_t)cbase * KP_ + kp16 + l15) * 32 + quad * 8;
  const ushort* fA = Ft + ((size_t)cbase * KP_ + kp16 + l15) * 32 + quad * 8;
  const ushort* kB0 = Kt + (((size_t)bh * 64 + cbase) * 32 + l15) * 32 + quad * 8;
  const ushort* kB1 = kB0 + 512;                   // e += 16
  const ushort* vB0 = Vt + (((size_t)bh * 64 + cbase) * 32 + l15) * 32 + quad * 8;
  const ushort* vB1 = vB0 + 512;

  f32x4 accK0 = {0.f,0.f,0.f,0.f}, accK1 = {0.f,0.f,0.f,0.f};
  f32x4 accV0 = {0.f,0.f,0.f,0.f}, accV1 = {0.f,0.f,0.f,0.f};

  BF8 e0, f0, k00, k10, v00, v10;   // buffer A
  BF8 e1, f1, k01, k11, v01, v11;   // buffer B

#define LPLD(E, F, K0, K1, V0, V1, I)                                   \
  do {                                                                  \
    (E).u4 = *reinterpret_cast<const uint4*>(eA + (size_t)(I) * (KP_ * 32)); \
    (F).u4 = *reinterpret_cast<const uint4*>(fA + (size_t)(I) * (KP_ * 32)); \
    (K0).u4 = *reinterpret_cast<const uint4*>(kB0 + (I) * CHK);         \
    (K1).u4 = *reinterpret_cast<const uint4*>(kB1 + (I) * CHK);         \
    (V0).u4 = *reinterpret_cast<const uint4*>(vB0 + (I) * CHK);         \
    (V1).u4 = *reinterpret_cast<const uint4*>(vB1 + (I) * CHK);         \
  } while (0)
#define LPMM(E, F, K0, K1, V0, V1)                                            \
  do {                                                                        \
    accK0 = __builtin_amdgcn_mfma_f32_16x16x32_bf16((E).b, (K0).b, accK0, 0, 0, 0); \
    accK1 = __builtin_amdgcn_mfma_f32_16x16x32_bf16((E).b, (K1).b, accK1, 0, 0, 0); \
    accV0 = __builtin_amdgcn_mfma_f32_16x16x32_bf16((F).b, (V0).b, accV0, 0, 0, 0); \
    accV1 = __builtin_amdgcn_mfma_f32_16x16x32_bf16((F).b, (V1).b, accV1, 0, 0, 0); \
  } while (0)

  LPLD(e0, f0, k00, k10, v00, v10, 0);
  LPLD(e1, f1, k01, k11, v01, v11, 1);
#pragma unroll
  for (int p = 0; p < 3; ++p) {
    LPMM(e0, f0, k00, k10, v00, v10);
    LPLD(e0, f0, k00, k10, v00, v10, 2 * p + 2);
    LPMM(e1, f1, k01, k11, v01, v11);
    LPLD(e1, f1, k01, k11, v01, v11, 2 * p + 3);
  }
  LPMM(e0, f0, k00, k10, v00, v10);
  LPMM(e1, f1, k01, k11, v01, v11);
#undef LPLD
#undef LPMM

#pragma unroll
  for (int r = 0; r < 4; ++r) {
    L[w][lane][r]      = accK0[r];
    L[w][lane][4 + r]  = accK1[r];
    L[w][lane][8 + r]  = accV0[r];
    L[w][lane][12 + r] = accV1[r];
  }
  __syncthreads();
  if (w < 4) {
#pragma unroll
    for (int r = 0; r < 4; ++r) {
      const float v = ((L[0][lane][w * 4 + r] + L[1][lane][w * 4 + r]) +
                       (L[2][lane][w * 4 + r] + L[3][lane][w * 4 + r])) +
                      ((L[4][lane][w * 4 + r] + L[5][lane][w * 4 + r]) +
                       (L[6][lane][w * 4 + r] + L[7][lane][w * 4 + r]));
      const int kp = kp16 + quad * 4 + r;
      if (w == 0)      Kp[((size_t)bh * KP_ + kp) * D_ + l15]       = f2bf(v);
      else if (w == 1) Kp[((size_t)bh * KP_ + kp) * D_ + 16 + l15]  = f2bf(v);
      else if (w == 2)  // VPC[bh][kp>>5][e=l15][kp&31]
        Vpt[(((size_t)bh * 8 + (kp >> 5)) * 32 + l15) * 32 + (kp & 31)] = f2bf(v);
      else
        Vpt[(((size_t)bh * 8 + (kp >> 5)) * 32 + 16 + l15) * 32 + (kp & 31)] = f2bf(v);
    }
  }
}

// ---------------------------------------------------------------------------
// Fused attention. Flat grid 2048 blocks of 256:
//   idx < 1024: causal full attention, quad-tile block (q rows [64m,64m+64)).
//     bh = (idx&7)+8*((idx>>3)&3) (XCD pinning), m = 31-(idx>>5) (LPT).
//     Waves k-split chunks [0,2m); wave 3 takes boundary chunk 2m, wave 2
//     takes chunk 2m+1. b128 bf16-packed LDS combine + broadcast Ls (17 KB).
//   idx >= 1024: Linformer attention (1024 blocks).
// ---------------------------------------------------------------------------
__global__ __launch_bounds__(256, 4) void k_attn(const float* __restrict__ Q,
                                                 const ushort* __restrict__ KH,
                                                 const ushort* __restrict__ Vt,
                                                 const ushort* __restrict__ Kp,
                                                 const ushort* __restrict__ Vpt,
                                                 float* __restrict__ out) {
  __shared__ alignas(16) unsigned Op[4][4][64][4];  // 16 KB packed O partials
  __shared__ float Ls[4][4][4][4];                  // 1 KB denom partials [w][tt][quad][r]
  const int idx = blockIdx.x;
  const int t = threadIdx.x;
  const int w = t >> 6, lane = t & 63;
  const int quad = lane >> 4, l15 = lane & 15;
  const int kperm1 = 8 * (l15 >> 2) + (l15 & 3);
  const f32x4 z = {0.f,0.f,0.f,0.f};

  BF8 ones;  // bf16 1.0 broadcast, B operand for row-sum MFMA
#pragma unroll
  for (int i2 = 0; i2 < 4; ++i2) ones.u32[i2] = 0x3F803F80u;

  if (idx < NFULL) {
    const int bh = (idx & 7) + 8 * ((idx >> 3) & 3);
    const int m = 31 - (idx >> 5);
    const int b = bh >> 3, h = bh & 7;
    const int q0 = 64 * m;

    BF8 qh[4];
#pragma unroll
    for (int tt = 0; tt < 4; ++tt)
      load8_bf(Q + ((size_t)(b * N_ + q0 + 16 * tt + l15) * H_ + h) * D_ + quad * 8,
               SCL2, qh[tt]);

    // per-lane base pointers. KH: permuted-packed rows (2KB/chunk contig).
    // VC: [bh][c][e][32k]; lane -> e=l15, k=quad*8+j; wave = contig 2KB.
    const ushort* KHl = KH + (size_t)bh * N_ * D_ + (size_t)kperm1 * D_ + quad * 8;
    const ushort* V0l = Vt + (size_t)bh * N_ * D_ + l15 * 32 + quad * 8;
    const ushort* V1l = V0l + 512;   // e += 16

    const int nun = 2 * m;                       // shared unmasked chunks
    const int cb = (w * nun) >> 2;
    const int ce = ((w + 1) * nun) >> 2;
    const int nwu = ce - cb;

    f32x4 O0[4], O1[4], LS[4];
#pragma unroll
    for (int tt = 0; tt < 4; ++tt) { O0[tt] = z; O1[tt] = z; LS[tt] = z; }

    BF8 kA1, kA2, vA0, vA1, kB1, kB2, vB0, vB1;

    auto procU = [&](BF8& k1, BF8& k2, BF8& v0, BF8& v1) {
      __builtin_amdgcn_s_setprio(1);
#pragma unroll
      for (int tt = 0; tt < 4; ++tt) {
        f32x4 s1 = __builtin_amdgcn_mfma_f32_16x16x32_bf16(k1.b, qh[tt].b, z, 0, 0, 0);
        f32x4 s2 = __builtin_amdgcn_mfma_f32_16x16x32_bf16(k2.b, qh[tt].b, z, 0, 0, 0);
        float e0 = ex2(s1[0]), e1 = ex2(s1[1]), e2 = ex2(s1[2]), e3 = ex2(s1[3]);
        float e4 = ex2(s2[0]), e5 = ex2(s2[1]), e6 = ex2(s2[2]), e7 = ex2(s2[3]);
        BF8 p;
        p.u32[0] = pkbf(e0, e1); p.u32[1] = pkbf(e2, e3);
        p.u32[2] = pkbf(e4, e5); p.u32[3] = pkbf(e6, e7);
        O0[tt] = __builtin_amdgcn_mfma_f32_16x16x32_bf16(p.b, v0.b, O0[tt], 0, 0, 0);
        O1[tt] = __builtin_amdgcn_mfma_f32_16x16x32_bf16(p.b, v1.b, O1[tt], 0, 0, 0);
        LS[tt] = __builtin_amdgcn_mfma_f32_16x16x32_bf16(p.b, ones.b, LS[tt], 0, 0, 0);
      }
      __builtin_amdgcn_s_setprio(0);
    };
    // masked pair (tiles ta: thr=l15, ta+1: thr=16+l15); tiles tb,tb+1 unmasked opt
    auto procM = [&](BF8& k1, BF8& k2, BF8& v0, BF8& v1, int ta, bool doUnm) {
      __builtin_amdgcn_s_setprio(1);
#pragma unroll
      for (int d = 0; d < 2; ++d) {
        const int tt = ta + d;
        const int thr = d ? 16 + l15 : l15;
        f32x4 s1 = __builtin_amdgcn_mfma_f32_16x16x32_bf16(k1.b, qh[tt].b, z, 0, 0, 0);
        f32x4 s2 = __builtin_amdgcn_mfma_f32_16x16x32_bf16(k2.b, qh[tt].b, z, 0, 0, 0);
        float e[8];
#pragma unroll
        for (int j = 0; j < 8; ++j) {
          const float sv = (j < 4) ? s1[j] : s2[j - 4];
          e[j] = (8 * quad + j <= thr) ? ex2(sv) : 0.f;
        }
        BF8 p;
        p.u32[0] = pkbf(e[0], e[1]); p.u32[1] = pkbf(e[2], e[3]);
        p.u32[2] = pkbf(e[4], e[5]); p.u32[3] = pkbf(e[6], e[7]);
        O0[tt] = __builtin_amdgcn_mfma_f32_16x16x32_bf16(p.b, v0.b, O0[tt], 0, 0, 0);
        O1[tt] = __builtin_amdgcn_mfma_f32_16x16x32_bf16(p.b, v1.b, O1[tt], 0, 0, 0);
        LS[tt] = __builtin_amdgcn_mfma_f32_16x16x32_bf16(p.b, ones.b, LS[tt], 0, 0, 0);
      }
      if (doUnm) {
#pragma unroll
        for (int tt = 2; tt < 4; ++tt) {
          f32x4 s1 = __builtin_amdgcn_mfma_f32_16x16x32_bf16(k1.b, qh[tt].b, z, 0, 0, 0);
          f32x4 s2 = __builtin_amdgcn_mfma_f32_16x16x32_bf16(k2.b, qh[tt].b, z, 0, 0, 0);
          float e0 = ex2(s1[0]), e1 = ex2(s1[1]), e2 = ex2(s1[2]), e3 = ex2(s1[3]);
          float e4 = ex2(s2[0]), e5 = ex2(s2[1]), e6 = ex2(s2[2]), e7 = ex2(s2[3]);
          BF8 p;
          p.u32[0] = pkbf(e0, e1); p.u32[1] = pkbf(e2, e3);
          p.u32[2] = pkbf(e4, e5); p.u32[3] = pkbf(e6, e7);
          O0[tt] = __builtin_amdgcn_mfma_f32_16x16x32_bf16(p.b, v0.b, O0[tt], 0, 0, 0);
          O1[tt] = __builtin_amdgcn_mfma_f32_16x16x32_bf16(p.b, v1.b, O1[tt], 0, 0, 0);
          LS[tt] = __builtin_amdgcn_mfma_f32_16x16x32_bf16(p.b, ones.b, LS[tt], 0, 0, 0);
        }
      }
      __builtin_amdgcn_s_setprio(0);
    };

    // initial loads: chunks cb (A) and cb+1 (B); over-reads stay in mapped ws
    kA1.u4 = *reinterpret_cast<const uint4*>(KHl + (size_t)cb * CHK);
    kA2.u4 = *reinterpret_cast<const uint4*>(KHl + (size_t)cb * CHK + 4 * D_);
    vA0.u4 = *reinterpret_cast<const uint4*>(V0l + (size_t)cb * CHK);
    vA1.u4 = *reinterpret_cast<const uint4*>(V1l + (size_t)cb * CHK);
    kB1.u4 = *reinterpret_cast<const uint4*>(KHl + (size_t)(cb + 1) * CHK);
    kB2.u4 = *reinterpret_cast<const uint4*>(KHl + (size_t)(cb + 1) * CHK + 4 * D_);
    vB0.u4 = *reinterpret_cast<const uint4*>(V0l + (size_t)(cb + 1) * CHK);
    vB1.u4 = *reinterpret_cast<const uint4*>(V1l + (size_t)(cb + 1) * CHK);

    const ushort* pKA = KHl + (size_t)(cb + 2) * CHK;
    const ushort* pKB = KHl + (size_t)(cb + 3) * CHK;
    const ushort* pV0 = V0l + (size_t)(cb + 2) * CHK;
    const ushort* pV1 = V1l + (size_t)(cb + 2) * CHK;

    int i = 0;
    for (; i + 2 <= nwu; i += 2) {
      procU(kA1, kA2, vA0, vA1);
      kA1.u4 = *reinterpret_cast<const uint4*>(pKA);
      kA2.u4 = *reinterpret_cast<const uint4*>(pKA + 4 * D_);
      vA0.u4 = *reinterpret_cast<const uint4*>(pV0);
      vA1.u4 = *reinterpret_cast<const uint4*>(pV1);
      procU(kB1, kB2, vB0, vB1);
      kB1.u4 = *reinterpret_cast<const uint4*>(pKB);
      kB2.u4 = *reinterpret_cast<const uint4*>(pKB + 4 * D_);
      vB0.u4 = *reinterpret_cast<const uint4*>(pV0 + CHK);
      vB1.u4 = *reinterpret_cast<const uint4*>(pV1 + CHK);
      pKA += 2 * CHK; pKB += 2 * CHK; pV0 += 2 * CHK; pV1 += 2 * CHK;
    }
    if (i < nwu) {  // one unmasked left in A; wave3's boundary chunk is in B
      procU(kA1, kA2, vA0, vA1);
      if (w == 3) procM(kB1, kB2, vB0, vB1, 0, true);
    } else if (w == 3) {  // boundary chunk nun is in A
      procM(kA1, kA2, vA0, vA1, 0, true);
    }
    if (w == 2) {  // boundary chunk nun+1 (cold load): tiles 2,3 masked
      const int c2 = nun + 1;
      kB1.u4 = *reinterpret_cast<const uint4*>(KHl + (size_t)c2 * CHK);
      kB2.u4 = *reinterpret_cast<const uint4*>(KHl + (size_t)c2 * CHK + 4 * D_);
      vB0.u4 = *reinterpret_cast<const uint4*>(V0l + (size_t)c2 * CHK);
      vB1.u4 = *reinterpret_cast<const uint4*>(V1l + (size_t)c2 * CHK);
      procM(kB1, kB2, vB0, vB1, 2, false);
    }

    // --- combine: b128 bf16-packed O partials + broadcast f32 denom ---
#pragma unroll
    for (int tt = 0; tt < 4; ++tt) {
      uint4 pk;
      pk.x = pkbf(O0[tt][0], O0[tt][1]);
      pk.y = pkbf(O0[tt][2], O0[tt][3]);
      pk.z = pkbf(O1[tt][0], O1[tt][1]);
      pk.w = pkbf(O1[tt][2], O1[tt][3]);
      *reinterpret_cast<uint4*>(Op[w][tt][lane]) = pk;
    }
    if (l15 == 0) {
#pragma unroll
      for (int tt = 0; tt < 4; ++tt)
#pragma unroll
        for (int r = 0; r < 4; ++r) Ls[w][tt][quad][r] = LS[tt][r];
    }
    __syncthreads();
    {
      const int tt = w;  // wave w writes tile w
      float iv[4];
#pragma unroll
      for (int r = 0; r < 4; ++r) {
        const float l = Ls[0][tt][quad][r] + Ls[1][tt][quad][r] +
                        Ls[2][tt][quad][r] + Ls[3][tt][quad][r];
        iv[r] = __builtin_amdgcn_rcpf(l);
      }
      float A0[4] = {0.f,0.f,0.f,0.f}, A1[4] = {0.f,0.f,0.f,0.f};
#pragma unroll
      for (int s = 0; s < 4; ++s) {
        const uint4 u = *reinterpret_cast<const uint4*>(Op[s][tt][lane]);
        A0[0] += bflo(u.x); A0[1] += bfhi(u.x);
        A0[2] += bflo(u.y); A0[3] += bfhi(u.y);
        A1[0] += bflo(u.z); A1[1] += bfhi(u.z);
        A1[2] += bflo(u.w); A1[3] += bfhi(u.w);
      }
#pragma unroll
      for (int r = 0; r < 4; ++r) {
        const int q = q0 + 16 * tt + quad * 4 + r;
        const size_t base = ((size_t)(b * N_ + q) * H_ + h) * D_;
        out[base + l15]      = A0[r] * iv[r];
        out[base + 16 + l15] = A1[r] * iv[r];
      }
    }
  } else {
    // ---- Linformer part ----
    const int j = idx - NFULL;
    const int bh = (j & 7) + 8 * ((j >> 3) & 3);
    const int b = bh >> 3, h = bh & 7;
    const int q0 = (j >> 5) * 64 + w * 16;
    float* olin = out + (size_t)B_ * N_ * H_ * D_;

    BF8 qh;
    load8_bf(Q + ((size_t)(b * N_ + q0 + l15) * H_ + h) * D_ + quad * 8, SCL2, qh);

    const int kperm2 = kperm1 + 4;
    const ushort* KpHb = Kp + (size_t)bh * KP_ * D_ + quad * 8;
    // VPC: [bh][g][e][32k]; lane -> e=l15, k=quad*8+j; wave = contig 2KB.
    const ushort* Vp0 = Vpt + (size_t)bh * KP_ * D_ + l15 * 32 + quad * 8;
    const ushort* Vp1 = Vp0 + 512;   // e += 16

    // raw exp + packed raw P; denominator via ones-MFMA (C rows quad*4+r
    // align with output rows); normalization deferred to the 8 outputs.
    BF8 pg[8];
    f32x4 LSum = z;
    __builtin_amdgcn_s_setprio(1);
#pragma unroll
    for (int g = 0; g < 8; ++g) {
      const int kp0 = g * 32;
      BF8 a1, a2;
      a1.u4 = *reinterpret_cast<const uint4*>(KpHb + (size_t)(kp0 + kperm1) * D_);
      a2.u4 = *reinterpret_cast<const uint4*>(KpHb + (size_t)(kp0 + kperm2) * D_);
      f32x4 s1 = __builtin_amdgcn_mfma_f32_16x16x32_bf16(a1.b, qh.b, z, 0, 0, 0);
      f32x4 s2 = __builtin_amdgcn_mfma_f32_16x16x32_bf16(a2.b, qh.b, z, 0, 0, 0);
      const float e0 = ex2(s1[0]), e1 = ex2(s1[1]), e2 = ex2(s1[2]), e3 = ex2(s1[3]);
      const float e4 = ex2(s2[0]), e5 = ex2(s2[1]), e6 = ex2(s2[2]), e7 = ex2(s2[3]);
      pg[g].u32[0] = pkbf(e0, e1); pg[g].u32[1] = pkbf(e2, e3);
      pg[g].u32[2] = pkbf(e4, e5); pg[g].u32[3] = pkbf(e6, e7);
      LSum = __builtin_amdgcn_mfma_f32_16x16x32_bf16(pg[g].b, ones.b, LSum, 0, 0, 0);
    }

    f32x4 O0 = z, O1 = z;
#pragma unroll
    for (int g = 0; g < 8; ++g) {
      BF8 v0, v1;
      v0.u4 = *reinterpret_cast<const uint4*>(Vp0 + g * CHK);
      v1.u4 = *reinterpret_cast<const uint4*>(Vp1 + g * CHK);
      O0 = __builtin_amdgcn_mfma_f32_16x16x32_bf16(pg[g].b, v0.b, O0, 0, 0, 0);
      O1 = __builtin_amdgcn_mfma_f32_16x16x32_bf16(pg[g].b, v1.b, O1, 0, 0, 0);
    }
    __builtin_amdgcn_s_setprio(0);

#pragma unroll
    for (int r = 0; r < 4; ++r) {
      const float fr = __builtin_amdgcn_rcpf(LSum[r]);
      const int q = q0 + quad * 4 + r;
      const size_t base = ((size_t)(b * N_ + q) * H_ + h) * D_;
      olin[base + l15]      = O0[r] * fr;
      olin[base + 16 + l15] = O1[r] * fr;
    }
  }
}

// ---------------------------------------------------------------------------
extern "C" void kernel_launch(void* const* d_in, const int* in_sizes, int n_in,
                              void* d_out, int out_size, void* d_ws, size_t ws_size,
                              hipStream_t stream) {
  const float* Q = (const float*)d_in[0];
  const float* K = (const float*)d_in[1];
  const float* V = (const float*)d_in[2];
  const float* E = (const float*)d_in[3];
  const float* F = (const float*)d_in[4];
  float* out = (float*)d_out;

  // workspace layout (ushort elements), ~15 MB total
  ushort* KH  = (ushort*)d_ws;                        // [BH][N][D]  4 MB
  ushort* Kt  = KH + (size_t)BH_ * N_ * D_;           // KC chunk-tiled 4 MB
  ushort* Vt  = Kt + (size_t)BH_ * N_ * D_;           // VC chunk-tiled 4 MB
  ushort* Et  = Vt + (size_t)BH_ * N_ * D_;           // EC chunk-tiled 1 MB
  ushort* Ft  = Et + (size_t)KP_ * N_;                // FC chunk-tiled 1 MB
  ushort* Kp  = Ft + (size_t)KP_ * N_;                // [BH][KP][D] 0.5 MB
  ushort* Vpt = Kp + (size_t)BH_ * KP_ * D_;          // VPC chunk-tiled 0.5 MB

  k_prep<<<dim3(1280), 256, 0, stream>>>(K, V, E, F, KH, Kt, Vt, Et, Ft);
  k_linproj<<<dim3(512), 512, 0, stream>>>(Et, Ft, Kt, Vt, Kp, Vpt);
  k_attn<<<dim3(NFULL + 1024), 256, 0, stream>>>(Q, KH, Vt, Kp, Vpt, out);
}

// Round 8
// 122.573 us; speedup vs baseline: 1.2220x; 1.0202x over previous
//
#include <hip/hip_runtime.h>
#include <hip/hip_bf16.h>

// dsfa_former: (1) causal full attention + (2) Linformer attention.
// Inputs fp32, outputs fp32. Internal bf16 MFMA, exp2 softmax (no-max:
// scores bounded, softmax is scale-free in fp32).
// B=4, N=2048, H=8, d=32, kproj=256.
//
// Round-18: SPILL-FREE MERGE. Round-7's coalesced layouts confirmed the
// gather theory (142->125us). Round-6's merge failed via scratch spills
// (pg[8] + runtime-indexed qh[w]); fixed here: Linformer PV interleaved
// per-g (one P fragment live), qh[w] selected via wave-uniform if-else.
// Grid 2048->1024 (one scheduling generation at 4 blocks/CU), deletes
// 1024 launches + 1024x(Q fetch+convert). Causal path byte-identical to
// round-7.
// Round-17 retained: chunk-tiled operand layouts (every wave-load = one
// contiguous 2KB burst): VC[bh][c][e][32k], KC same, EC/FC[c][kp][32k],
// VPC[bh][g][e][32k].
// Round-14 retained: linproj 8-wave ping-pong, prep packed converts.
// Round-11 retained: raw v_exp_f32, ones-MFMA softmax denominator,
// b128 packed LDS combine + broadcast Ls, deferred 1/l normalization.
// Round-10 retained: quad-tile blocks, ping-pong prefetch, S^T trick.
//
// Fragment layouts (learn_hip m89/m91/m120):
//   C/D: per-lane row = quad*4 + reg, col = lane&15
//   A:   lane holds A[m = lane&15][k = quad*8 + j], j=0..7
//   B:   lane holds B[k = quad*8 + j][n = lane&15]

typedef __bf16 bf16x8 __attribute__((ext_vector_type(8)));
typedef __bf16 bf16x2 __attribute__((ext_vector_type(2)));
typedef float f32x4 __attribute__((ext_vector_type(4)));

union BF8 { uint4 u4; ushort us[8]; bf16x8 b; unsigned u32[4]; };

constexpr int B_ = 4, N_ = 2048, H_ = 8, D_ = 32, KP_ = 256, BH_ = 32;
constexpr float SCL2 = 0.25505654442633533f;  // (1/sqrt(32)) * log2(e)
constexpr int NFULL = 1024;                   // merged blocks
constexpr int CHK = 32 * D_;                  // chunk stride (ushorts) = 1024

__device__ __forceinline__ ushort f2bf(float f) {
  unsigned u = __builtin_bit_cast(unsigned, f);
  return (ushort)((u + 0x7FFFu + ((u >> 16) & 1u)) >> 16);
}
// pack two floats -> bf16 pair (lo = first arg)
__device__ __forceinline__ unsigned pkbf(float f0, float f1) {
#if __has_builtin(__builtin_amdgcn_cvt_pk_bf16_f32)
  bf16x2 r = __builtin_amdgcn_cvt_pk_bf16_f32(f0, f1);
  return __builtin_bit_cast(unsigned, r);
#else
  unsigned u0 = __builtin_bit_cast(unsigned, f0) + 0x8000u;
  unsigned u1 = __builtin_bit_cast(unsigned, f1) + 0x8000u;
  return __builtin_amdgcn_perm(u1, u0, 0x07060302);  // [u1.hi : u0.hi]
#endif
}
__device__ __forceinline__ float bflo(unsigned u) {
  return __builtin_bit_cast(float, u << 16);
}
__device__ __forceinline__ float bfhi(unsigned u) {
  return __builtin_bit_cast(float, u & 0xFFFF0000u);
}
// raw v_exp_f32: scores bounded, no -inf fed in, denormal output flushes
// to 0 which is exactly what softmax wants.
__device__ __forceinline__ float ex2(float x) {
#if __has_builtin(__builtin_amdgcn_exp2f)
  return __builtin_amdgcn_exp2f(x);
#else
  return exp2f(x);
#endif
}

__device__ __forceinline__ void load8_bf(const float* __restrict__ p,
                                         float scale, BF8& hi) {
  float4 a = *reinterpret_cast<const float4*>(p);
  float4 b = *reinterpret_cast<const float4*>(p + 4);
  float x[8] = {a.x, a.y, a.z, a.w, b.x, b.y, b.z, b.w};
#pragma unroll
  for (int i = 0; i < 8; ++i) hi.us[i] = f2bf(x[i] * scale);
}

// ---------------------------------------------------------------------------
// Fused prep. Flat grid 1280 blocks of 256:
//   idx < 1024: K -> KH[bh][n][e] bf16 (permuted-packed),
//               K -> KC[bh][c][e][32k], V -> VC[bh][c][e][32k]
//   idx >= 1024: E -> EC[c][kp][32k] bf16 / F -> FC (256 blocks)
// ---------------------------------------------------------------------------
__global__ __launch_bounds__(256) void k_prep(const float* __restrict__ K,
                                              const float* __restrict__ V,
                                              const float* __restrict__ E,
                                              const float* __restrict__ F,
                                              ushort* __restrict__ KH,
                                              ushort* __restrict__ Kt,
                                              ushort* __restrict__ Vt,
                                              ushort* __restrict__ Et,
                                              ushort* __restrict__ Ft) {
  __shared__ alignas(16) ushort S[4224];
  const int idx = blockIdx.x;
  const int t = threadIdx.x;
  if (idx < 1024) {
    ushort* Tk = S;            // [e][n_local] stride 66
    ushort* Tv = S + 2112;
    const int bh = idx >> 5, b = bh >> 3, h = bh & 7;
    const int n0 = (idx & 31) * 64;
    {
      const int row = t >> 2, e8 = (t & 3) * 8;
      const size_t gbase = ((size_t)(b * N_ + n0 + row) * H_ + h) * D_ + e8;
      float4 k0 = *reinterpret_cast<const float4*>(K + gbase);
      float4 k1 = *reinterpret_cast<const float4*>(K + gbase + 4);
      float4 v0 = *reinterpret_cast<const float4*>(V + gbase);
      float4 v1 = *reinterpret_cast<const float4*>(V + gbase + 4);
      float kk[8] = {k0.x,k0.y,k0.z,k0.w,k1.x,k1.y,k1.z,k1.w};
      float vv[8] = {v0.x,v0.y,v0.z,v0.w,v1.x,v1.y,v1.z,v1.w};
      BF8 xh, vh;
#pragma unroll
      for (int i = 0; i < 4; ++i) {
        xh.u32[i] = pkbf(kk[2 * i], kk[2 * i + 1]);
        vh.u32[i] = pkbf(vv[2 * i], vv[2 * i + 1]);
      }
#pragma unroll
      for (int i = 0; i < 8; ++i) {
        Tk[(e8 + i) * 66 + row] = xh.us[i];
        Tv[(e8 + i) * 66 + row] = vh.us[i];
      }
      *reinterpret_cast<uint4*>(KH + ((size_t)bh * N_ + n0 + row) * D_ + e8) = xh.u4;
    }
    __syncthreads();
    {
      const int e = t >> 3, n8 = (t & 7) * 8;
      BF8 xk, xv;
#pragma unroll
      for (int i = 0; i < 8; ++i) {
        xk.us[i] = Tk[e * 66 + n8 + i];
        xv.us[i] = Tv[e * 66 + n8 + i];
      }
      // chunk-tiled: [bh][c][e][32k]
      const int c = (n0 + n8) >> 5, k = n8 & 31;
      const size_t ob = (((size_t)bh * 64 + c) * 32 + e) * 32 + k;
      *reinterpret_cast<uint4*>(Kt + ob) = xk.u4;
      *reinterpret_cast<uint4*>(Vt + ob) = xv.u4;
    }
  } else {
    const int j = idx - 1024;
    const float* src = (j >> 7) ? F : E;
    ushort* dst = (j >> 7) ? Ft : Et;
    const int jj = j & 127;
    const int n0 = (jj & 31) * 64, kp0 = (jj >> 5) * 64;
    ushort* T = S;  // [kp_local][n_local] stride 66
    {
      const int n = t >> 2, c16 = (t & 3) * 16;
      const size_t gbase = (size_t)(n0 + n) * KP_ + kp0 + c16;
#pragma unroll
      for (int q = 0; q < 4; ++q) {
        float4 x = *reinterpret_cast<const float4*>(src + gbase + q * 4);
        const unsigned u01 = pkbf(x.x, x.y), u23 = pkbf(x.z, x.w);
        T[(c16 + q * 4 + 0) * 66 + n] = (ushort)u01;
        T[(c16 + q * 4 + 1) * 66 + n] = (ushort)(u01 >> 16);
        T[(c16 + q * 4 + 2) * 66 + n] = (ushort)u23;
        T[(c16 + q * 4 + 3) * 66 + n] = (ushort)(u23 >> 16);
      }
    }
    __syncthreads();
    {
      const int kp = t >> 2, n16 = (t & 3) * 16;
      BF8 x0, x1;
#pragma unroll
      for (int i = 0; i < 8; ++i) {
        x0.us[i] = T[kp * 66 + n16 + i];
        x1.us[i] = T[kp * 66 + n16 + 8 + i];
      }
      // chunk-tiled: [c][kp][32k]
      const int c = (n0 + n16) >> 5, k = n16 & 31;
      const size_t ob = ((size_t)c * KP_ + kp0 + kp) * 32 + k;
      *reinterpret_cast<uint4*>(dst + ob) = x0.u4;
      *reinterpret_cast<uint4*>(dst + ob + 8) = x1.u4;
    }
  }
}

// ---------------------------------------------------------------------------
// Kernel: Kp[bh][kp][e] (bf16) and VPC[bh][g][e][32k]. Flat grid 512 blocks
// of 512 threads (8 waves, N/8 per wave), XCD-pinned bh, ping-pong prefetch,
// LDS combine over 8 partials. All global reads contiguous 2KB per wave-load.
// ---------------------------------------------------------------------------
__global__ __launch_bounds__(512) void k_linproj(const ushort* __restrict__ Et,
                                                 const ushort* __restrict__ Ft,
                                                 const ushort* __restrict__ Kt,
                                                 const ushort* __restrict__ Vt,
                                                 ushort* __restrict__ Kp,
                                                 ushort* __restrict__ Vpt) {
  __shared__ float L[8][64][16];  // 32 KB
  const int id = blockIdx.x;
  const int bh = (id & 7) + 8 * ((id >> 3) & 3);   // XCD pinning
  const int kp16 = (id >> 5) * 16;
  const int t = threadIdx.x;
  const int w = t >> 6, lane = t & 63, quad = lane >> 4, l15 = lane & 15;
  const int cbase = w * 8;                          // 8 chunks of 32 per wave

  // EC/FC: (c*KP + kp)*32 + k ; KC/VC: ((bh*64 + c)*32 + e)*32 + k
  const ushort* eA = Et + ((size_t)cbase * KP_ + kp16 + l15) * 32 + quad * 8;
  const ushort* fA = Ft + ((size_t)cbase * KP_ + kp16 + l15) * 32 + quad * 8;
  const ushort* kB0 = Kt + (((size_t)bh * 64 + cbase) * 32 + l15) * 32 + quad * 8;
  const ushort* kB1 = kB0 + 512;                   // e += 16
  const ushort* vB0 = Vt + (((size_t)bh * 64 + cbase) * 32 + l15) * 32 + quad * 8;
  const ushort* vB1 = vB0 + 512;

  f32x4 accK0 = {0.f,0.f,0.f,0.f}, accK1 = {0.f,0.f,0.f,0.f};
  f32x4 accV0 = {0.f,0.f,0.f,0.f}, accV1 = {0.f,0.f,0.f,0.f};

  BF8 e0, f0, k00, k10, v00, v10;   // buffer A
  BF8 e1, f1, k01, k11, v01, v11;   // buffer B

#define LPLD(E, F, K0, K1, V0, V1, I)                                   \
  do {                                                                  \
    (E).u4 = *reinterpret_cast<const uint4*>(eA + (size_t)(I) * (KP_ * 32)); \
    (F).u4 = *reinterpret_cast<const uint4*>(fA + (size_t)(I) * (KP_ * 32)); \
    (K0).u4 = *reinterpret_cast<const uint4*>(kB0 + (I) * CHK);         \
    (K1).u4 = *reinterpret_cast<const uint4*>(kB1 + (I) * CHK);         \
    (V0).u4 = *reinterpret_cast<const uint4*>(vB0 + (I) * CHK);         \
    (V1).u4 = *reinterpret_cast<const uint4*>(vB1 + (I) * CHK);         \
  } while (0)
#define LPMM(E, F, K0, K1, V0, V1)                                            \
  do {                                                                        \
    accK0 = __builtin_amdgcn_mfma_f32_16x16x32_bf16((E).b, (K0).b, accK0, 0, 0, 0); \
    accK1 = __builtin_amdgcn_mfma_f32_16x16x32_bf16((E).b, (K1).b, accK1, 0, 0, 0); \
    accV0 = __builtin_amdgcn_mfma_f32_16x16x32_bf16((F).b, (V0).b, accV0, 0, 0, 0); \
    accV1 = __builtin_amdgcn_mfma_f32_16x16x32_bf16((F).b, (V1).b, accV1, 0, 0, 0); \
  } while (0)

  LPLD(e0, f0, k00, k10, v00, v10, 0);
  LPLD(e1, f1, k01, k11, v01, v11, 1);
#pragma unroll
  for (int p = 0; p < 3; ++p) {
    LPMM(e0, f0, k00, k10, v00, v10);
    LPLD(e0, f0, k00, k10, v00, v10, 2 * p + 2);
    LPMM(e1, f1, k01, k11, v01, v11);
    LPLD(e1, f1, k01, k11, v01, v11, 2 * p + 3);
  }
  LPMM(e0, f0, k00, k10, v00, v10);
  LPMM(e1, f1, k01, k11, v01, v11);
#undef LPLD
#undef LPMM

#pragma unroll
  for (int r = 0; r < 4; ++r) {
    L[w][lane][r]      = accK0[r];
    L[w][lane][4 + r]  = accK1[r];
    L[w][lane][8 + r]  = accV0[r];
    L[w][lane][12 + r] = accV1[r];
  }
  __syncthreads();
  if (w < 4) {
#pragma unroll
    for (int r = 0; r < 4; ++r) {
      const float v = ((L[0][lane][w * 4 + r] + L[1][lane][w * 4 + r]) +
                       (L[2][lane][w * 4 + r] + L[3][lane][w * 4 + r])) +
                      ((L[4][lane][w * 4 + r] + L[5][lane][w * 4 + r]) +
                       (L[6][lane][w * 4 + r] + L[7][lane][w * 4 + r]));
      const int kp = kp16 + quad * 4 + r;
      if (w == 0)      Kp[((size_t)bh * KP_ + kp) * D_ + l15]       = f2bf(v);
      else if (w == 1) Kp[((size_t)bh * KP_ + kp) * D_ + 16 + l15]  = f2bf(v);
      else if (w == 2)  // VPC[bh][kp>>5][e=l15][kp&31]
        Vpt[(((size_t)bh * 8 + (kp >> 5)) * 32 + l15) * 32 + (kp & 31)] = f2bf(v);
      else
        Vpt[(((size_t)bh * 8 + (kp >> 5)) * 32 + 16 + l15) * 32 + (kp & 31)] = f2bf(v);
    }
  }
}

// ---------------------------------------------------------------------------
// Merged attention. Grid 1024 blocks of 256 (4 waves):
//   Causal full attention, quad-tile block (q rows [64m,64m+64)).
//   bh = (idx&7)+8*((idx>>3)&3) (XCD pinning), m = 31-(idx>>5) (LPT).
//   Waves k-split chunks [0,2m); wave 3 takes boundary chunk 2m, wave 2
//   takes chunk 2m+1. b128 bf16-packed LDS combine + broadcast Ls (17 KB).
//   Then: Linformer for the SAME 64 rows, wave w = rows [16w,16w+16),
//   reusing qh[w] (wave-uniform select, no runtime indexing), PV
//   interleaved per-g so only one P fragment is live (no pg[8] spill).
// ---------------------------------------------------------------------------
__global__ __launch_bounds__(256, 4) void k_attn(const float* __restrict__ Q,
                                                 const ushort* __restrict__ KH,
                                                 const ushort* __restrict__ Vt,
                                                 const ushort* __restrict__ Kp,
                                                 const ushort* __restrict__ Vpt,
                                                 float* __restrict__ out) {
  __shared__ alignas(16) unsigned Op[4][4][64][4];  // 16 KB packed O partials
  __shared__ float Ls[4][4][4][4];                  // 1 KB denom partials [w][tt][quad][r]
  const int idx = blockIdx.x;
  const int t = threadIdx.x;
  const int w = t >> 6, lane = t & 63;
  const int quad = lane >> 4, l15 = lane & 15;
  const int kperm1 = 8 * (l15 >> 2) + (l15 & 3);
  const f32x4 z = {0.f,0.f,0.f,0.f};

  BF8 ones;  // bf16 1.0 broadcast, B operand for row-sum MFMA
#pragma unroll
  for (int i2 = 0; i2 < 4; ++i2) ones.u32[i2] = 0x3F803F80u;

  const int bh = (idx & 7) + 8 * ((idx >> 3) & 3);
  const int m = 31 - (idx >> 5);
  const int b = bh >> 3, h = bh & 7;
  const int q0 = 64 * m;

  BF8 qh[4];
#pragma unroll
  for (int tt = 0; tt < 4; ++tt)
    load8_bf(Q + ((size_t)(b * N_ + q0 + 16 * tt + l15) * H_ + h) * D_ + quad * 8,
             SCL2, qh[tt]);

  {
    // per-lane base pointers. KH: permuted-packed rows (2KB/chunk contig).
    // VC: [bh][c][e][32k]; lane -> e=l15, k=quad*8+j; wave = contig 2KB.
    const ushort* KHl = KH + (size_t)bh * N_ * D_ + (size_t)kperm1 * D_ + quad * 8;
    const ushort* V0l = Vt + (size_t)bh * N_ * D_ + l15 * 32 + quad * 8;
    const ushort* V1l = V0l + 512;   // e += 16

    const int nun = 2 * m;                       // shared unmasked chunks
    const int cb = (w * nun) >> 2;
    const int ce = ((w + 1) * nun) >> 2;
    const int nwu = ce - cb;

    f32x4 O0[4], O1[4], LS[4];
#pragma unroll
    for (int tt = 0; tt < 4; ++tt) { O0[tt] = z; O1[tt] = z; LS[tt] = z; }

    BF8 kA1, kA2, vA0, vA1, kB1, kB2, vB0, vB1;

    auto procU = [&](BF8& k1, BF8& k2, BF8& v0, BF8& v1) {
      __builtin_amdgcn_s_setprio(1);
#pragma unroll
      for (int tt = 0; tt < 4; ++tt) {
        f32x4 s1 = __builtin_amdgcn_mfma_f32_16x16x32_bf16(k1.b, qh[tt].b, z, 0, 0, 0);
        f32x4 s2 = __builtin_amdgcn_mfma_f32_16x16x32_bf16(k2.b, qh[tt].b, z, 0, 0, 0);
        float e0 = ex2(s1[0]), e1 = ex2(s1[1]), e2 = ex2(s1[2]), e3 = ex2(s1[3]);
        float e4 = ex2(s2[0]), e5 = ex2(s2[1]), e6 = ex2(s2[2]), e7 = ex2(s2[3]);
        BF8 p;
        p.u32[0] = pkbf(e0, e1); p.u32[1] = pkbf(e2, e3);
        p.u32[2] = pkbf(e4, e5); p.u32[3] = pkbf(e6, e7);
        O0[tt] = __builtin_amdgcn_mfma_f32_16x16x32_bf16(p.b, v0.b, O0[tt], 0, 0, 0);
        O1[tt] = __builtin_amdgcn_mfma_f32_16x16x32_bf16(p.b, v1.b, O1[tt], 0, 0, 0);
        LS[tt] = __builtin_amdgcn_mfma_f32_16x16x32_bf16(p.b, ones.b, LS[tt], 0, 0, 0);
      }
      __builtin_amdgcn_s_setprio(0);
    };
    // masked pair (tiles ta: thr=l15, ta+1: thr=16+l15); tiles tb,tb+1 unmasked opt
    auto procM = [&](BF8& k1, BF8& k2, BF8& v0, BF8& v1, int ta, bool doUnm) {
      __builtin_amdgcn_s_setprio(1);
#pragma unroll
      for (int d = 0; d < 2; ++d) {
        const int tt = ta + d;
        const int thr = d ? 16 + l15 : l15;
        f32x4 s1 = __builtin_amdgcn_mfma_f32_16x16x32_bf16(k1.b, qh[tt].b, z, 0, 0, 0);
        f32x4 s2 = __builtin_amdgcn_mfma_f32_16x16x32_bf16(k2.b, qh[tt].b, z, 0, 0, 0);
        float e[8];
#pragma unroll
        for (int j = 0; j < 8; ++j) {
          const float sv = (j < 4) ? s1[j] : s2[j - 4];
          e[j] = (8 * quad + j <= thr) ? ex2(sv) : 0.f;
        }
        BF8 p;
        p.u32[0] = pkbf(e[0], e[1]); p.u32[1] = pkbf(e[2], e[3]);
        p.u32[2] = pkbf(e[4], e[5]); p.u32[3] = pkbf(e[6], e[7]);
        O0[tt] = __builtin_amdgcn_mfma_f32_16x16x32_bf16(p.b, v0.b, O0[tt], 0, 0, 0);
        O1[tt] = __builtin_amdgcn_mfma_f32_16x16x32_bf16(p.b, v1.b, O1[tt], 0, 0, 0);
        LS[tt] = __builtin_amdgcn_mfma_f32_16x16x32_bf16(p.b, ones.b, LS[tt], 0, 0, 0);
      }
      if (doUnm) {
#pragma unroll
        for (int tt = 2; tt < 4; ++tt) {
          f32x4 s1 = __builtin_amdgcn_mfma_f32_16x16x32_bf16(k1.b, qh[tt].b, z, 0, 0, 0);
          f32x4 s2 = __builtin_amdgcn_mfma_f32_16x16x32_bf16(k2.b, qh[tt].b, z, 0, 0, 0);
          float e0 = ex2(s1[0]), e1 = ex2(s1[1]), e2 = ex2(s1[2]), e3 = ex2(s1[3]);
          float e4 = ex2(s2[0]), e5 = ex2(s2[1]), e6 = ex2(s2[2]), e7 = ex2(s2[3]);
          BF8 p;
          p.u32[0] = pkbf(e0, e1); p.u32[1] = pkbf(e2, e3);
          p.u32[2] = pkbf(e4, e5); p.u32[3] = pkbf(e6, e7);
          O0[tt] = __builtin_amdgcn_mfma_f32_16x16x32_bf16(p.b, v0.b, O0[tt], 0, 0, 0);
          O1[tt] = __builtin_amdgcn_mfma_f32_16x16x32_bf16(p.b, v1.b, O1[tt], 0, 0, 0);
          LS[tt] = __builtin_amdgcn_mfma_f32_16x16x32_bf16(p.b, ones.b, LS[tt], 0, 0, 0);
        }
      }
      __builtin_amdgcn_s_setprio(0);
    };

    // initial loads: chunks cb (A) and cb+1 (B); over-reads stay in mapped ws
    kA1.u4 = *reinterpret_cast<const uint4*>(KHl + (size_t)cb * CHK);
    kA2.u4 = *reinterpret_cast<const uint4*>(KHl + (size_t)cb * CHK + 4 * D_);
    vA0.u4 = *reinterpret_cast<const uint4*>(V0l + (size_t)cb * CHK);
    vA1.u4 = *reinterpret_cast<const uint4*>(V1l + (size_t)cb * CHK);
    kB1.u4 = *reinterpret_cast<const uint4*>(KHl + (size_t)(cb + 1) * CHK);
    kB2.u4 = *reinterpret_cast<const uint4*>(KHl + (size_t)(cb + 1) * CHK + 4 * D_);
    vB0.u4 = *reinterpret_cast<const uint4*>(V0l + (size_t)(cb + 1) * CHK);
    vB1.u4 = *reinterpret_cast<const uint4*>(V1l + (size_t)(cb + 1) * CHK);

    const ushort* pKA = KHl + (size_t)(cb + 2) * CHK;
    const ushort* pKB = KHl + (size_t)(cb + 3) * CHK;
    const ushort* pV0 = V0l + (size_t)(cb + 2) * CHK;
    const ushort* pV1 = V1l + (size_t)(cb + 2) * CHK;

    int i = 0;
    for (; i + 2 <= nwu; i += 2) {
      procU(kA1, kA2, vA0, vA1);
      kA1.u4 = *reinterpret_cast<const uint4*>(pKA);
      kA2.u4 = *reinterpret_cast<const uint4*>(pKA + 4 * D_);
      vA0.u4 = *reinterpret_cast<const uint4*>(pV0);
      vA1.u4 = *reinterpret_cast<const uint4*>(pV1);
      procU(kB1, kB2, vB0, vB1);
      kB1.u4 = *reinterpret_cast<const uint4*>(pKB);
      kB2.u4 = *reinterpret_cast<const uint4*>(pKB + 4 * D_);
      vB0.u4 = *reinterpret_cast<const uint4*>(pV0 + CHK);
      vB1.u4 = *reinterpret_cast<const uint4*>(pV1 + CHK);
      pKA += 2 * CHK; pKB += 2 * CHK; pV0 += 2 * CHK; pV1 += 2 * CHK;
    }
    if (i < nwu) {  // one unmasked left in A; wave3's boundary chunk is in B
      procU(kA1, kA2, vA0, vA1);
      if (w == 3) procM(kB1, kB2, vB0, vB1, 0, true);
    } else if (w == 3) {  // boundary chunk nun is in A
      procM(kA1, kA2, vA0, vA1, 0, true);
    }
    if (w == 2) {  // boundary chunk nun+1 (cold load): tiles 2,3 masked
      const int c2 = nun + 1;
      kB1.u4 = *reinterpret_cast<const uint4*>(KHl + (size_t)c2 * CHK);
      kB2.u4 = *reinterpret_cast<const uint4*>(KHl + (size_t)c2 * CHK + 4 * D_);
      vB0.u4 = *reinterpret_cast<const uint4*>(V0l + (size_t)c2 * CHK);
      vB1.u4 = *reinterpret_cast<const uint4*>(V1l + (size_t)c2 * CHK);
      procM(kB1, kB2, vB0, vB1, 2, false);
    }

    // --- combine: b128 bf16-packed O partials + broadcast f32 denom ---
#pragma unroll
    for (int tt = 0; tt < 4; ++tt) {
      uint4 pk;
      pk.x = pkbf(O0[tt][0], O0[tt][1]);
      pk.y = pkbf(O0[tt][2], O0[tt][3]);
      pk.z = pkbf(O1[tt][0], O1[tt][1]);
      pk.w = pkbf(O1[tt][2], O1[tt][3]);
      *reinterpret_cast<uint4*>(Op[w][tt][lane]) = pk;
    }
    if (l15 == 0) {
#pragma unroll
      for (int tt = 0; tt < 4; ++tt)
#pragma unroll
        for (int r = 0; r < 4; ++r) Ls[w][tt][quad][r] = LS[tt][r];
    }
    __syncthreads();
    {
      const int tt = w;  // wave w writes tile w
      float iv[4];
#pragma unroll
      for (int r = 0; r < 4; ++r) {
        const float l = Ls[0][tt][quad][r] + Ls[1][tt][quad][r] +
                        Ls[2][tt][quad][r] + Ls[3][tt][quad][r];
        iv[r] = __builtin_amdgcn_rcpf(l);
      }
      float A0[4] = {0.f,0.f,0.f,0.f}, A1[4] = {0.f,0.f,0.f,0.f};
#pragma unroll
      for (int s = 0; s < 4; ++s) {
        const uint4 u = *reinterpret_cast<const uint4*>(Op[s][tt][lane]);
        A0[0] += bflo(u.x); A0[1] += bfhi(u.x);
        A0[2] += bflo(u.y); A0[3] += bfhi(u.y);
        A1[0] += bflo(u.z); A1[1] += bfhi(u.z);
        A1[2] += bflo(u.w); A1[3] += bfhi(u.w);
      }
#pragma unroll
      for (int r = 0; r < 4; ++r) {
        const int q = q0 + 16 * tt + quad * 4 + r;
        const size_t base = ((size_t)(b * N_ + q) * H_ + h) * D_;
        out[base + l15]      = A0[r] * iv[r];
        out[base + 16 + l15] = A1[r] * iv[r];
      }
    }
  }

  // ---- Linformer for this block's rows: wave w = rows [16w,16w+16) ----
  {
    // wave-uniform select of qh[w] (no runtime-indexed array -> no scratch)
    BF8 qsel = qh[0];
    if (w == 1) qsel = qh[1];
    else if (w == 2) qsel = qh[2];
    else if (w == 3) qsel = qh[3];

    float* olin = out + (size_t)B_ * N_ * H_ * D_;
    const int q0l = q0 + 16 * w;

    const int kperm2 = kperm1 + 4;
    const ushort* KpHb = Kp + (size_t)bh * KP_ * D_ + quad * 8;
    // VPC: [bh][g][e][32k]; lane -> e=l15, k=quad*8+j; wave = contig 2KB.
    const ushort* Vp0 = Vpt + (size_t)bh * KP_ * D_ + l15 * 32 + quad * 8;
    const ushort* Vp1 = Vp0 + 512;   // e += 16

    // Interleaved per-g: score -> exp -> pack -> LSum/O MFMAs immediately;
    // one P fragment live at a time. Normalization deferred to outputs.
    f32x4 LSum = z, O0 = z, O1 = z;
    __builtin_amdgcn_s_setprio(1);
#pragma unroll
    for (int g = 0; g < 8; ++g) {
      const int kp0 = g * 32;
      BF8 a1, a2, v0, v1;
      a1.u4 = *reinterpret_cast<const uint4*>(KpHb + (size_t)(kp0 + kperm1) * D_);
      a2.u4 = *reinterpret_cast<const uint4*>(KpHb + (size_t)(kp0 + kperm2) * D_);
      v0.u4 = *reinterpret_cast<const uint4*>(Vp0 + g * CHK);
      v1.u4 = *reinterpret_cast<const uint4*>(Vp1 + g * CHK);
      f32x4 s1 = __builtin_amdgcn_mfma_f32_16x16x32_bf16(a1.b, qsel.b, z, 0, 0, 0);
      f32x4 s2 = __builtin_amdgcn_mfma_f32_16x16x32_bf16(a2.b, qsel.b, z, 0, 0, 0);
      const float e0 = ex2(s1[0]), e1 = ex2(s1[1]), e2 = ex2(s1[2]), e3 = ex2(s1[3]);
      const float e4 = ex2(s2[0]), e5 = ex2(s2[1]), e6 = ex2(s2[2]), e7 = ex2(s2[3]);
      BF8 p;
      p.u32[0] = pkbf(e0, e1); p.u32[1] = pkbf(e2, e3);
      p.u32[2] = pkbf(e4, e5); p.u32[3] = pkbf(e6, e7);
      LSum = __builtin_amdgcn_mfma_f32_16x16x32_bf16(p.b, ones.b, LSum, 0, 0, 0);
      O0 = __builtin_amdgcn_mfma_f32_16x16x32_bf16(p.b, v0.b, O0, 0, 0, 0);
      O1 = __builtin_amdgcn_mfma_f32_16x16x32_bf16(p.b, v1.b, O1, 0, 0, 0);
    }
    __builtin_amdgcn_s_setprio(0);

#pragma unroll
    for (int r = 0; r < 4; ++r) {
      const float fr = __builtin_amdgcn_rcpf(LSum[r]);
      const int q = q0l + quad * 4 + r;
      const size_t base = ((size_t)(b * N_ + q) * H_ + h) * D_;
      olin[base + l15]      = O0[r] * fr;
      olin[base + 16 + l15] = O1[r] * fr;
    }
  }
}

// ---------------------------------------------------------------------------
extern "C" void kernel_launch(void* const* d_in, const int* in_sizes, int n_in,
                              void* d_out, int out_size, void* d_ws, size_t ws_size,
                              hipStream_t stream) {
  const float* Q = (const float*)d_in[0];
  const float* K = (const float*)d_in[1];
  const float* V = (const float*)d_in[2];
  const float* E = (const float*)d_in[3];
  const float* F = (const float*)d_in[4];
  float* out = (float*)d_out;

  // workspace layout (ushort elements), ~15 MB total
  ushort* KH  = (ushort*)d_ws;                        // [BH][N][D]  4 MB
  ushort* Kt  = KH + (size_t)BH_ * N_ * D_;           // KC chunk-tiled 4 MB
  ushort* Vt  = Kt + (size_t)BH_ * N_ * D_;           // VC chunk-tiled 4 MB
  ushort* Et  = Vt + (size_t)BH_ * N_ * D_;           // EC chunk-tiled 1 MB
  ushort* Ft  = Et + (size_t)KP_ * N_;                // FC chunk-tiled 1 MB
  ushort* Kp  = Ft + (size_t)KP_ * N_;                // [BH][KP][D] 0.5 MB
  ushort* Vpt = Kp + (size_t)BH_ * KP_ * D_;          // VPC chunk-tiled 0.5 MB

  k_prep<<<dim3(1280), 256, 0, stream>>>(K, V, E, F, KH, Kt, Vt, Et, Ft);
  k_linproj<<<dim3(512), 512, 0, stream>>>(Et, Ft, Kt, Vt, Kp, Vpt);
  k_attn<<<dim3(NFULL), 256, 0, stream>>>(Q, KH, Vt, Kp, Vpt, out);
}

// Round 9
// 122.498 us; speedup vs baseline: 1.2228x; 1.0006x over previous
//
#include <hip/hip_runtime.h>
#include <hip/hip_bf16.h>

// dsfa_former: (1) causal full attention + (2) Linformer attention.
// Inputs fp32, outputs fp32. Internal bf16 MFMA, exp2 softmax (no-max:
// scores bounded, softmax is scale-free in fp32).
// B=4, N=2048, H=8, d=32, kproj=256.
//
// Round-19: FULL COALESCING. Round-7 proved the governing mechanism
// (per-wave-load transaction count on the critical chain) by packing V;
// K was still a 16-line gather (kperm rows at 64B stride), Q prologue a
// ~32-transaction strided gather, Linformer Kp the same. Now ALL attn
// wave-loads are contiguous 1KB bursts:
//   KHP[bh][c][half][l15p][e]  (kA1 = c*1024, kA2 = +512)
//   QHP[bh][m][tt][l15][e]     (SCL2 pre-applied; 4 loads, no converts)
//   KPP[bh][g][half][l15p][e]  (a1 = g*1024, a2 = +512)
//   VC/VPC/EC/FC chunk-tiled (round-17).
// attn drops kperm entirely. prep additionally stages Q (+1 read/pack).
// Round-18 retained: merged causal+Linformer blocks (grid 1024),
// interleaved per-g Linformer PV (no pg[8]), wave-uniform qh select.
// Round-14/11/10 retained: linproj 8-wave ping-pong, packed converts,
// raw v_exp_f32, ones-MFMA denominator, b128 packed LDS combine,
// deferred 1/l normalization, quad-tile blocks, ping-pong prefetch.
//
// Fragment layouts (learn_hip m89/m91/m120):
//   C/D: per-lane row = quad*4 + reg, col = lane&15
//   A:   lane holds A[m = lane&15][k = quad*8 + j], j=0..7
//   B:   lane holds B[k = quad*8 + j][n = lane&15]

typedef __bf16 bf16x8 __attribute__((ext_vector_type(8)));
typedef __bf16 bf16x2 __attribute__((ext_vector_type(2)));
typedef float f32x4 __attribute__((ext_vector_type(4)));

union BF8 { uint4 u4; ushort us[8]; bf16x8 b; unsigned u32[4]; };

constexpr int B_ = 4, N_ = 2048, H_ = 8, D_ = 32, KP_ = 256, BH_ = 32;
constexpr float SCL2 = 0.25505654442633533f;  // (1/sqrt(32)) * log2(e)
constexpr int NFULL = 1024;                   // merged blocks
constexpr int CHK = 32 * D_;                  // chunk stride (ushorts) = 1024

__device__ __forceinline__ ushort f2bf(float f) {
  unsigned u = __builtin_bit_cast(unsigned, f);
  return (ushort)((u + 0x7FFFu + ((u >> 16) & 1u)) >> 16);
}
// pack two floats -> bf16 pair (lo = first arg)
__device__ __forceinline__ unsigned pkbf(float f0, float f1) {
#if __has_builtin(__builtin_amdgcn_cvt_pk_bf16_f32)
  bf16x2 r = __builtin_amdgcn_cvt_pk_bf16_f32(f0, f1);
  return __builtin_bit_cast(unsigned, r);
#else
  unsigned u0 = __builtin_bit_cast(unsigned, f0) + 0x8000u;
  unsigned u1 = __builtin_bit_cast(unsigned, f1) + 0x8000u;
  return __builtin_amdgcn_perm(u1, u0, 0x07060302);  // [u1.hi : u0.hi]
#endif
}
__device__ __forceinline__ float bflo(unsigned u) {
  return __builtin_bit_cast(float, u << 16);
}
__device__ __forceinline__ float bfhi(unsigned u) {
  return __builtin_bit_cast(float, u & 0xFFFF0000u);
}
// raw v_exp_f32: scores bounded, no -inf fed in, denormal output flushes
// to 0 which is exactly what softmax wants.
__device__ __forceinline__ float ex2(float x) {
#if __has_builtin(__builtin_amdgcn_exp2f)
  return __builtin_amdgcn_exp2f(x);
#else
  return exp2f(x);
#endif
}

// ---------------------------------------------------------------------------
// Fused prep. Flat grid 1280 blocks of 256:
//   idx < 1024: K -> KHP (attn lane order), K -> KC[bh][c][e][32k],
//               V -> VC[bh][c][e][32k], Q -> QHP (scaled, attn lane order)
//   idx >= 1024: E -> EC[c][kp][32k] bf16 / F -> FC (256 blocks)
// ---------------------------------------------------------------------------
__global__ __launch_bounds__(256) void k_prep(const float* __restrict__ Qf,
                                              const float* __restrict__ K,
                                              const float* __restrict__ V,
                                              const float* __restrict__ E,
                                              const float* __restrict__ F,
                                              ushort* __restrict__ KH,
                                              ushort* __restrict__ Kt,
                                              ushort* __restrict__ Vt,
                                              ushort* __restrict__ Et,
                                              ushort* __restrict__ Ft,
                                              ushort* __restrict__ QH) {
  __shared__ alignas(16) ushort S[4224];
  const int idx = blockIdx.x;
  const int t = threadIdx.x;
  if (idx < 1024) {
    ushort* Tk = S;            // [e][n_local] stride 66
    ushort* Tv = S + 2112;
    const int bh = idx >> 5, b = bh >> 3, h = bh & 7;
    const int n0 = (idx & 31) * 64;
    {
      const int row = t >> 2, e8 = (t & 3) * 8;
      const size_t gbase = ((size_t)(b * N_ + n0 + row) * H_ + h) * D_ + e8;
      float4 k0 = *reinterpret_cast<const float4*>(K + gbase);
      float4 k1 = *reinterpret_cast<const float4*>(K + gbase + 4);
      float4 v0 = *reinterpret_cast<const float4*>(V + gbase);
      float4 v1 = *reinterpret_cast<const float4*>(V + gbase + 4);
      float4 q0 = *reinterpret_cast<const float4*>(Qf + gbase);
      float4 q1 = *reinterpret_cast<const float4*>(Qf + gbase + 4);
      float kk[8] = {k0.x,k0.y,k0.z,k0.w,k1.x,k1.y,k1.z,k1.w};
      float vv[8] = {v0.x,v0.y,v0.z,v0.w,v1.x,v1.y,v1.z,v1.w};
      float qq[8] = {q0.x,q0.y,q0.z,q0.w,q1.x,q1.y,q1.z,q1.w};
      BF8 xh, vh, qp;
#pragma unroll
      for (int i = 0; i < 4; ++i) {
        xh.u32[i] = pkbf(kk[2 * i], kk[2 * i + 1]);
        vh.u32[i] = pkbf(vv[2 * i], vv[2 * i + 1]);
        qp.u32[i] = pkbf(qq[2 * i] * SCL2, qq[2 * i + 1] * SCL2);
      }
#pragma unroll
      for (int i = 0; i < 8; ++i) {
        Tk[(e8 + i) * 66 + row] = xh.us[i];
        Tv[(e8 + i) * 66 + row] = vh.us[i];
      }
      // KHP: [bh][c][half][l15p][e] — attn kA1/kA2 lane order
      {
        const int n32 = row & 31;
        const int cg = (idx & 31) * 2 + (row >> 5);
        const int half = (n32 >> 2) & 1;
        const int l15p = 4 * (n32 >> 3) + (n32 & 3);
        *reinterpret_cast<uint4*>(
            KH + (((size_t)bh * 64 + cg) * 2 + half) * 512 + l15p * 32 + e8) = xh.u4;
      }
      // QHP: [bh][m][tt][l15][e] — attn qh lane order, SCL2 pre-applied
      {
        const int mq = idx & 31;
        const int tq = (row >> 4) & 3, l15q = row & 15;
        *reinterpret_cast<uint4*>(
            QH + (((size_t)bh * 32 + mq) * 4 + tq) * 512 + l15q * 32 + e8) = qp.u4;
      }
    }
    __syncthreads();
    {
      const int e = t >> 3, n8 = (t & 7) * 8;
      BF8 xk, xv;
#pragma unroll
      for (int i = 0; i < 8; ++i) {
        xk.us[i] = Tk[e * 66 + n8 + i];
        xv.us[i] = Tv[e * 66 + n8 + i];
      }
      // chunk-tiled: [bh][c][e][32k]
      const int c = (n0 + n8) >> 5, k = n8 & 31;
      const size_t ob = (((size_t)bh * 64 + c) * 32 + e) * 32 + k;
      *reinterpret_cast<uint4*>(Kt + ob) = xk.u4;
      *reinterpret_cast<uint4*>(Vt + ob) = xv.u4;
    }
  } else {
    const int j = idx - 1024;
    const float* src = (j >> 7) ? F : E;
    ushort* dst = (j >> 7) ? Ft : Et;
    const int jj = j & 127;
    const int n0 = (jj & 31) * 64, kp0 = (jj >> 5) * 64;
    ushort* T = S;  // [kp_local][n_local] stride 66
    {
      const int n = t >> 2, c16 = (t & 3) * 16;
      const size_t gbase = (size_t)(n0 + n) * KP_ + kp0 + c16;
#pragma unroll
      for (int q = 0; q < 4; ++q) {
        float4 x = *reinterpret_cast<const float4*>(src + gbase + q * 4);
        const unsigned u01 = pkbf(x.x, x.y), u23 = pkbf(x.z, x.w);
        T[(c16 + q * 4 + 0) * 66 + n] = (ushort)u01;
        T[(c16 + q * 4 + 1) * 66 + n] = (ushort)(u01 >> 16);
        T[(c16 + q * 4 + 2) * 66 + n] = (ushort)u23;
        T[(c16 + q * 4 + 3) * 66 + n] = (ushort)(u23 >> 16);
      }
    }
    __syncthreads();
    {
      const int kp = t >> 2, n16 = (t & 3) * 16;
      BF8 x0, x1;
#pragma unroll
      for (int i = 0; i < 8; ++i) {
        x0.us[i] = T[kp * 66 + n16 + i];
        x1.us[i] = T[kp * 66 + n16 + 8 + i];
      }
      // chunk-tiled: [c][kp][32k]
      const int c = (n0 + n16) >> 5, k = n16 & 31;
      const size_t ob = ((size_t)c * KP_ + kp0 + kp) * 32 + k;
      *reinterpret_cast<uint4*>(dst + ob) = x0.u4;
      *reinterpret_cast<uint4*>(dst + ob + 8) = x1.u4;
    }
  }
}

// ---------------------------------------------------------------------------
// Kernel: KPP[bh][g][half][l15p][e] (bf16) and VPC[bh][g][e][32k]. Flat grid
// 512 blocks of 512 threads (8 waves, N/8 per wave), XCD-pinned bh,
// ping-pong prefetch, LDS combine over 8 partials. All global reads
// contiguous 2KB per wave-load.
// ---------------------------------------------------------------------------
__global__ __launch_bounds__(512) void k_linproj(const ushort* __restrict__ Et,
                                                 const ushort* __restrict__ Ft,
                                                 const ushort* __restrict__ Kt,
                                                 const ushort* __restrict__ Vt,
                                                 ushort* __restrict__ Kp,
                                                 ushort* __restrict__ Vpt) {
  __shared__ float L[8][64][16];  // 32 KB
  const int id = blockIdx.x;
  const int bh = (id & 7) + 8 * ((id >> 3) & 3);   // XCD pinning
  const int kp16 = (id >> 5) * 16;
  const int t = threadIdx.x;
  const int w = t >> 6, lane = t & 63, quad = lane >> 4, l15 = lane & 15;
  const int cbase = w * 8;                          // 8 chunks of 32 per wave

  // EC/FC: (c*KP + kp)*32 + k ; KC/VC: ((bh*64 + c)*32 + e)*32 + k
  const ushort* eA = Et + ((size_t)cbase * KP_ + kp16 + l15) * 32 + quad * 8;
  const ushort* fA = Ft + ((size_t)cbase * KP_ + kp16 + l15) * 32 + quad * 8;
  const ushort* kB0 = Kt + (((size_t)bh * 64 + cbase) * 32 + l15) * 32 + quad * 8;
  const ushort* kB1 = kB0 + 512;                   // e += 16
  const ushort* vB0 = Vt + (((size_t)bh * 64 + cbase) * 32 + l15) * 32 + quad * 8;
  const ushort* vB1 = vB0 + 512;

  f32x4 accK0 = {0.f,0.f,0.f,0.f}, accK1 = {0.f,0.f,0.f,0.f};
  f32x4 accV0 = {0.f,0.f,0.f,0.f}, accV1 = {0.f,0.f,0.f,0.f};

  BF8 e0, f0, k00, k10, v00, v10;   // buffer A
  BF8 e1, f1, k01, k11, v01, v11;   // buffer B

#define LPLD(E, F, K0, K1, V0, V1, I)                                   \
  do {                                                                  \
    (E).u4 = *reinterpret_cast<const uint4*>(eA + (size_t)(I) * (KP_ * 32)); \
    (F).u4 = *reinterpret_cast<const uint4*>(fA + (size_t)(I) * (KP_ * 32)); \
    (K0).u4 = *reinterpret_cast<const uint4*>(kB0 + (I) * CHK);         \
    (K1).u4 = *reinterpret_cast<const uint4*>(kB1 + (I) * CHK);         \
    (V0).u4 = *reinterpret_cast<const uint4*>(vB0 + (I) * CHK);         \
    (V1).u4 = *reinterpret_cast<const uint4*>(vB1 + (I) * CHK);         \
  } while (0)
#define LPMM(E, F, K0, K1, V0, V1)                                            \
  do {                                                                        \
    accK0 = __builtin_amdgcn_mfma_f32_16x16x32_bf16((E).b, (K0).b, accK0, 0, 0, 0); \
    accK1 = __builtin_amdgcn_mfma_f32_16x16x32_bf16((E).b, (K1).b, accK1, 0, 0, 0); \
    accV0 = __builtin_amdgcn_mfma_f32_16x16x32_bf16((F).b, (V0).b, accV0, 0, 0, 0); \
    accV1 = __builtin_amdgcn_mfma_f32_16x16x32_bf16((F).b, (V1).b, accV1, 0, 0, 0); \
  } while (0)

  LPLD(e0, f0, k00, k10, v00, v10, 0);
  LPLD(e1, f1, k01, k11, v01, v11, 1);
#pragma unroll
  for (int p = 0; p < 3; ++p) {
    LPMM(e0, f0, k00, k10, v00, v10);
    LPLD(e0, f0, k00, k10, v00, v10, 2 * p + 2);
    LPMM(e1, f1, k01, k11, v01, v11);
    LPLD(e1, f1, k01, k11, v01, v11, 2 * p + 3);
  }
  LPMM(e0, f0, k00, k10, v00, v10);
  LPMM(e1, f1, k01, k11, v01, v11);
#undef LPLD
#undef LPMM

#pragma unroll
  for (int r = 0; r < 4; ++r) {
    L[w][lane][r]      = accK0[r];
    L[w][lane][4 + r]  = accK1[r];
    L[w][lane][8 + r]  = accV0[r];
    L[w][lane][12 + r] = accV1[r];
  }
  __syncthreads();
  if (w < 4) {
#pragma unroll
    for (int r = 0; r < 4; ++r) {
      const float v = ((L[0][lane][w * 4 + r] + L[1][lane][w * 4 + r]) +
                       (L[2][lane][w * 4 + r] + L[3][lane][w * 4 + r])) +
                      ((L[4][lane][w * 4 + r] + L[5][lane][w * 4 + r]) +
                       (L[6][lane][w * 4 + r] + L[7][lane][w * 4 + r]));
      const int kp = kp16 + quad * 4 + r;
      if (w < 2) {
        // KPP: [bh][g][half][l15p][e] — attn a1/a2 lane order
        const int g = kp >> 5, n32 = kp & 31;
        const int half = (n32 >> 2) & 1;
        const int l15p = 4 * (n32 >> 3) + (n32 & 3);
        const int e = (w == 0) ? l15 : 16 + l15;
        Kp[(((size_t)bh * 8 + g) * 2 + half) * 512 + l15p * 32 + e] = f2bf(v);
      } else if (w == 2) {  // VPC[bh][kp>>5][e=l15][kp&31]
        Vpt[(((size_t)bh * 8 + (kp >> 5)) * 32 + l15) * 32 + (kp & 31)] = f2bf(v);
      } else {
        Vpt[(((size_t)bh * 8 + (kp >> 5)) * 32 + 16 + l15) * 32 + (kp & 31)] = f2bf(v);
      }
    }
  }
}

// ---------------------------------------------------------------------------
// Merged attention. Grid 1024 blocks of 256 (4 waves):
//   Causal full attention, quad-tile block (q rows [64m,64m+64)).
//   bh = (idx&7)+8*((idx>>3)&3) (XCD pinning), m = 31-(idx>>5) (LPT).
//   Waves k-split chunks [0,2m); wave 3 takes boundary chunk 2m, wave 2
//   takes chunk 2m+1. b128 bf16-packed LDS combine + broadcast Ls (17 KB).
//   Then: Linformer for the SAME 64 rows, wave w = rows [16w,16w+16),
//   reusing qh[w] (wave-uniform select), PV interleaved per-g.
//   ALL wave-loads are contiguous 1KB bursts (KHP/QHP/KPP/VC/VPC).
// ---------------------------------------------------------------------------
__global__ __launch_bounds__(256, 4) void k_attn(const ushort* __restrict__ QH,
                                                 const ushort* __restrict__ KH,
                                                 const ushort* __restrict__ Vt,
                                                 const ushort* __restrict__ Kp,
                                                 const ushort* __restrict__ Vpt,
                                                 float* __restrict__ out) {
  __shared__ alignas(16) unsigned Op[4][4][64][4];  // 16 KB packed O partials
  __shared__ float Ls[4][4][4][4];                  // 1 KB denom partials [w][tt][quad][r]
  const int idx = blockIdx.x;
  const int t = threadIdx.x;
  const int w = t >> 6, lane = t & 63;
  const int quad = lane >> 4, l15 = lane & 15;
  const f32x4 z = {0.f,0.f,0.f,0.f};

  BF8 ones;  // bf16 1.0 broadcast, B operand for row-sum MFMA
#pragma unroll
  for (int i2 = 0; i2 < 4; ++i2) ones.u32[i2] = 0x3F803F80u;

  const int bh = (idx & 7) + 8 * ((idx >> 3) & 3);
  const int m = 31 - (idx >> 5);
  const int b = bh >> 3, h = bh & 7;
  const int q0 = 64 * m;
  const int laneoff = l15 * 32 + quad * 8;

  // QHP: [bh][m][tt][l15][e] — 4 coalesced 1KB wave-loads, pre-scaled
  BF8 qh[4];
  {
    const ushort* QHl = QH + (((size_t)bh * 32 + m) * 4) * 512 + laneoff;
#pragma unroll
    for (int tt = 0; tt < 4; ++tt)
      qh[tt].u4 = *reinterpret_cast<const uint4*>(QHl + tt * 512);
  }

  {
    // KHP: [bh][c][half][l15p][e]; kA1 = c*1024, kA2 = +512 (1KB bursts).
    // VC: [bh][c][e][32k]; v0 = c*1024, v1 = +512.
    const ushort* KHl = KH + (size_t)bh * N_ * D_ + laneoff;
    const ushort* V0l = Vt + (size_t)bh * N_ * D_ + l15 * 32 + quad * 8;
    const ushort* V1l = V0l + 512;   // e += 16

    const int nun = 2 * m;                       // shared unmasked chunks
    const int cb = (w * nun) >> 2;
    const int ce = ((w + 1) * nun) >> 2;
    const int nwu = ce - cb;

    f32x4 O0[4], O1[4], LS[4];
#pragma unroll
    for (int tt = 0; tt < 4; ++tt) { O0[tt] = z; O1[tt] = z; LS[tt] = z; }

    BF8 kA1, kA2, vA0, vA1, kB1, kB2, vB0, vB1;

    auto procU = [&](BF8& k1, BF8& k2, BF8& v0, BF8& v1) {
      __builtin_amdgcn_s_setprio(1);
#pragma unroll
      for (int tt = 0; tt < 4; ++tt) {
        f32x4 s1 = __builtin_amdgcn_mfma_f32_16x16x32_bf16(k1.b, qh[tt].b, z, 0, 0, 0);
        f32x4 s2 = __builtin_amdgcn_mfma_f32_16x16x32_bf16(k2.b, qh[tt].b, z, 0, 0, 0);
        float e0 = ex2(s1[0]), e1 = ex2(s1[1]), e2 = ex2(s1[2]), e3 = ex2(s1[3]);
        float e4 = ex2(s2[0]), e5 = ex2(s2[1]), e6 = ex2(s2[2]), e7 = ex2(s2[3]);
        BF8 p;
        p.u32[0] = pkbf(e0, e1); p.u32[1] = pkbf(e2, e3);
        p.u32[2] = pkbf(e4, e5); p.u32[3] = pkbf(e6, e7);
        O0[tt] = __builtin_amdgcn_mfma_f32_16x16x32_bf16(p.b, v0.b, O0[tt], 0, 0, 0);
        O1[tt] = __builtin_amdgcn_mfma_f32_16x16x32_bf16(p.b, v1.b, O1[tt], 0, 0, 0);
        LS[tt] = __builtin_amdgcn_mfma_f32_16x16x32_bf16(p.b, ones.b, LS[tt], 0, 0, 0);
      }
      __builtin_amdgcn_s_setprio(0);
    };
    // masked pair (tiles ta: thr=l15, ta+1: thr=16+l15); tiles tb,tb+1 unmasked opt
    auto procM = [&](BF8& k1, BF8& k2, BF8& v0, BF8& v1, int ta, bool doUnm) {
      __builtin_amdgcn_s_setprio(1);
#pragma unroll
      for (int d = 0; d < 2; ++d) {
        const int tt = ta + d;
        const int thr = d ? 16 + l15 : l15;
        f32x4 s1 = __builtin_amdgcn_mfma_f32_16x16x32_bf16(k1.b, qh[tt].b, z, 0, 0, 0);
        f32x4 s2 = __builtin_amdgcn_mfma_f32_16x16x32_bf16(k2.b, qh[tt].b, z, 0, 0, 0);
        float e[8];
#pragma unroll
        for (int j = 0; j < 8; ++j) {
          const float sv = (j < 4) ? s1[j] : s2[j - 4];
          e[j] = (8 * quad + j <= thr) ? ex2(sv) : 0.f;
        }
        BF8 p;
        p.u32[0] = pkbf(e[0], e[1]); p.u32[1] = pkbf(e[2], e[3]);
        p.u32[2] = pkbf(e[4], e[5]); p.u32[3] = pkbf(e[6], e[7]);
        O0[tt] = __builtin_amdgcn_mfma_f32_16x16x32_bf16(p.b, v0.b, O0[tt], 0, 0, 0);
        O1[tt] = __builtin_amdgcn_mfma_f32_16x16x32_bf16(p.b, v1.b, O1[tt], 0, 0, 0);
        LS[tt] = __builtin_amdgcn_mfma_f32_16x16x32_bf16(p.b, ones.b, LS[tt], 0, 0, 0);
      }
      if (doUnm) {
#pragma unroll
        for (int tt = 2; tt < 4; ++tt) {
          f32x4 s1 = __builtin_amdgcn_mfma_f32_16x16x32_bf16(k1.b, qh[tt].b, z, 0, 0, 0);
          f32x4 s2 = __builtin_amdgcn_mfma_f32_16x16x32_bf16(k2.b, qh[tt].b, z, 0, 0, 0);
          float e0 = ex2(s1[0]), e1 = ex2(s1[1]), e2 = ex2(s1[2]), e3 = ex2(s1[3]);
          float e4 = ex2(s2[0]), e5 = ex2(s2[1]), e6 = ex2(s2[2]), e7 = ex2(s2[3]);
          BF8 p;
          p.u32[0] = pkbf(e0, e1); p.u32[1] = pkbf(e2, e3);
          p.u32[2] = pkbf(e4, e5); p.u32[3] = pkbf(e6, e7);
          O0[tt] = __builtin_amdgcn_mfma_f32_16x16x32_bf16(p.b, v0.b, O0[tt], 0, 0, 0);
          O1[tt] = __builtin_amdgcn_mfma_f32_16x16x32_bf16(p.b, v1.b, O1[tt], 0, 0, 0);
          LS[tt] = __builtin_amdgcn_mfma_f32_16x16x32_bf16(p.b, ones.b, LS[tt], 0, 0, 0);
        }
      }
      __builtin_amdgcn_s_setprio(0);
    };

    // initial loads: chunks cb (A) and cb+1 (B); over-reads stay in mapped ws
    kA1.u4 = *reinterpret_cast<const uint4*>(KHl + (size_t)cb * CHK);
    kA2.u4 = *reinterpret_cast<const uint4*>(KHl + (size_t)cb * CHK + 512);
    vA0.u4 = *reinterpret_cast<const uint4*>(V0l + (size_t)cb * CHK);
    vA1.u4 = *reinterpret_cast<const uint4*>(V1l + (size_t)cb * CHK);
    kB1.u4 = *reinterpret_cast<const uint4*>(KHl + (size_t)(cb + 1) * CHK);
    kB2.u4 = *reinterpret_cast<const uint4*>(KHl + (size_t)(cb + 1) * CHK + 512);
    vB0.u4 = *reinterpret_cast<const uint4*>(V0l + (size_t)(cb + 1) * CHK);
    vB1.u4 = *reinterpret_cast<const uint4*>(V1l + (size_t)(cb + 1) * CHK);

    const ushort* pKA = KHl + (size_t)(cb + 2) * CHK;
    const ushort* pKB = KHl + (size_t)(cb + 3) * CHK;
    const ushort* pV0 = V0l + (size_t)(cb + 2) * CHK;
    const ushort* pV1 = V1l + (size_t)(cb + 2) * CHK;

    int i = 0;
    for (; i + 2 <= nwu; i += 2) {
      procU(kA1, kA2, vA0, vA1);
      kA1.u4 = *reinterpret_cast<const uint4*>(pKA);
      kA2.u4 = *reinterpret_cast<const uint4*>(pKA + 512);
      vA0.u4 = *reinterpret_cast<const uint4*>(pV0);
      vA1.u4 = *reinterpret_cast<const uint4*>(pV1);
      procU(kB1, kB2, vB0, vB1);
      kB1.u4 = *reinterpret_cast<const uint4*>(pKB);
      kB2.u4 = *reinterpret_cast<const uint4*>(pKB + 512);
      vB0.u4 = *reinterpret_cast<const uint4*>(pV0 + CHK);
      vB1.u4 = *reinterpret_cast<const uint4*>(pV1 + CHK);
      pKA += 2 * CHK; pKB += 2 * CHK; pV0 += 2 * CHK; pV1 += 2 * CHK;
    }
    if (i < nwu) {  // one unmasked left in A; wave3's boundary chunk is in B
      procU(kA1, kA2, vA0, vA1);
      if (w == 3) procM(kB1, kB2, vB0, vB1, 0, true);
    } else if (w == 3) {  // boundary chunk nun is in A
      procM(kA1, kA2, vA0, vA1, 0, true);
    }
    if (w == 2) {  // boundary chunk nun+1 (cold load): tiles 2,3 masked
      const int c2 = nun + 1;
      kB1.u4 = *reinterpret_cast<const uint4*>(KHl + (size_t)c2 * CHK);
      kB2.u4 = *reinterpret_cast<const uint4*>(KHl + (size_t)c2 * CHK + 512);
      vB0.u4 = *reinterpret_cast<const uint4*>(V0l + (size_t)c2 * CHK);
      vB1.u4 = *reinterpret_cast<const uint4*>(V1l + (size_t)c2 * CHK);
      procM(kB1, kB2, vB0, vB1, 2, false);
    }

    // --- combine: b128 bf16-packed O partials + broadcast f32 denom ---
#pragma unroll
    for (int tt = 0; tt < 4; ++tt) {
      uint4 pk;
      pk.x = pkbf(O0[tt][0], O0[tt][1]);
      pk.y = pkbf(O0[tt][2], O0[tt][3]);
      pk.z = pkbf(O1[tt][0], O1[tt][1]);
      pk.w = pkbf(O1[tt][2], O1[tt][3]);
      *reinterpret_cast<uint4*>(Op[w][tt][lane]) = pk;
    }
    if (l15 == 0) {
#pragma unroll
      for (int tt = 0; tt < 4; ++tt)
#pragma unroll
        for (int r = 0; r < 4; ++r) Ls[w][tt][quad][r] = LS[tt][r];
    }
    __syncthreads();
    {
      const int tt = w;  // wave w writes tile w
      float iv[4];
#pragma unroll
      for (int r = 0; r < 4; ++r) {
        const float l = Ls[0][tt][quad][r] + Ls[1][tt][quad][r] +
                        Ls[2][tt][quad][r] + Ls[3][tt][quad][r];
        iv[r] = __builtin_amdgcn_rcpf(l);
      }
      float A0[4] = {0.f,0.f,0.f,0.f}, A1[4] = {0.f,0.f,0.f,0.f};
#pragma unroll
      for (int s = 0; s < 4; ++s) {
        const uint4 u = *reinterpret_cast<const uint4*>(Op[s][tt][lane]);
        A0[0] += bflo(u.x); A0[1] += bfhi(u.x);
        A0[2] += bflo(u.y); A0[3] += bfhi(u.y);
        A1[0] += bflo(u.z); A1[1] += bfhi(u.z);
        A1[2] += bflo(u.w); A1[3] += bfhi(u.w);
      }
#pragma unroll
      for (int r = 0; r < 4; ++r) {
        const int q = q0 + 16 * tt + quad * 4 + r;
        const size_t base = ((size_t)(b * N_ + q) * H_ + h) * D_;
        out[base + l15]      = A0[r] * iv[r];
        out[base + 16 + l15] = A1[r] * iv[r];
      }
    }
  }

  // ---- Linformer for this block's rows: wave w = rows [16w,16w+16) ----
  {
    // wave-uniform select of qh[w] (no runtime-indexed array -> no scratch)
    BF8 qsel = qh[0];
    if (w == 1) qsel = qh[1];
    else if (w == 2) qsel = qh[2];
    else if (w == 3) qsel = qh[3];

    float* olin = out + (size_t)B_ * N_ * H_ * D_;
    const int q0l = q0 + 16 * w;

    // KPP: [bh][g][half][l15p][e]; a1 = g*1024, a2 = +512 (1KB bursts).
    const ushort* KpL = Kp + (size_t)bh * KP_ * D_ + laneoff;
    // VPC: [bh][g][e][32k]; v0 = g*1024, v1 = +512.
    const ushort* Vp0 = Vpt + (size_t)bh * KP_ * D_ + l15 * 32 + quad * 8;
    const ushort* Vp1 = Vp0 + 512;   // e += 16

    // Interleaved per-g: score -> exp -> pack -> LSum/O MFMAs immediately;
    // one P fragment live at a time. Normalization deferred to outputs.
    f32x4 LSum = z, O0 = z, O1 = z;
    __builtin_amdgcn_s_setprio(1);
#pragma unroll
    for (int g = 0; g < 8; ++g) {
      BF8 a1, a2, v0, v1;
      a1.u4 = *reinterpret_cast<const uint4*>(KpL + g * CHK);
      a2.u4 = *reinterpret_cast<const uint4*>(KpL + g * CHK + 512);
      v0.u4 = *reinterpret_cast<const uint4*>(Vp0 + g * CHK);
      v1.u4 = *reinterpret_cast<const uint4*>(Vp1 + g * CHK);
      f32x4 s1 = __builtin_amdgcn_mfma_f32_16x16x32_bf16(a1.b, qsel.b, z, 0, 0, 0);
      f32x4 s2 = __builtin_amdgcn_mfma_f32_16x16x32_bf16(a2.b, qsel.b, z, 0, 0, 0);
      const float e0 = ex2(s1[0]), e1 = ex2(s1[1]), e2 = ex2(s1[2]), e3 = ex2(s1[3]);
      const float e4 = ex2(s2[0]), e5 = ex2(s2[1]), e6 = ex2(s2[2]), e7 = ex2(s2[3]);
      BF8 p;
      p.u32[0] = pkbf(e0, e1); p.u32[1] = pkbf(e2, e3);
      p.u32[2] = pkbf(e4, e5); p.u32[3] = pkbf(e6, e7);
      LSum = __builtin_amdgcn_mfma_f32_16x16x32_bf16(p.b, ones.b, LSum, 0, 0, 0);
      O0 = __builtin_amdgcn_mfma_f32_16x16x32_bf16(p.b, v0.b, O0, 0, 0, 0);
      O1 = __builtin_amdgcn_mfma_f32_16x16x32_bf16(p.b, v1.b, O1, 0, 0, 0);
    }
    __builtin_amdgcn_s_setprio(0);

#pragma unroll
    for (int r = 0; r < 4; ++r) {
      const float fr = __builtin_amdgcn_rcpf(LSum[r]);
      const int q = q0l + quad * 4 + r;
      const size_t base = ((size_t)(b * N_ + q) * H_ + h) * D_;
      olin[base + l15]      = O0[r] * fr;
      olin[base + 16 + l15] = O1[r] * fr;
    }
  }
}

// ---------------------------------------------------------------------------
extern "C" void kernel_launch(void* const* d_in, const int* in_sizes, int n_in,
                              void* d_out, int out_size, void* d_ws, size_t ws_size,
                              hipStream_t stream) {
  const float* Q = (const float*)d_in[0];
  const float* K = (const float*)d_in[1];
  const float* V = (const float*)d_in[2];
  const float* E = (const float*)d_in[3];
  const float* F = (const float*)d_in[4];
  float* out = (float*)d_out;

  // workspace layout (ushort elements), ~19 MB total
  ushort* KH  = (ushort*)d_ws;                        // KHP packed    4 MB
  ushort* Kt  = KH + (size_t)BH_ * N_ * D_;           // KC chunk-tiled 4 MB
  ushort* Vt  = Kt + (size_t)BH_ * N_ * D_;           // VC chunk-tiled 4 MB
  ushort* Et  = Vt + (size_t)BH_ * N_ * D_;           // EC chunk-tiled 1 MB
  ushort* Ft  = Et + (size_t)KP_ * N_;                // FC chunk-tiled 1 MB
  ushort* Kp  = Ft + (size_t)KP_ * N_;                // KPP packed   0.5 MB
  ushort* Vpt = Kp + (size_t)BH_ * KP_ * D_;          // VPC chunk-tiled 0.5 MB
  ushort* QHP = Vpt + (size_t)BH_ * KP_ * D_;         // QHP packed    4 MB

  k_prep<<<dim3(1280), 256, 0, stream>>>(Q, K, V, E, F, KH, Kt, Vt, Et, Ft, QHP);
  k_linproj<<<dim3(512), 512, 0, stream>>>(Et, Ft, Kt, Vt, Kp, Vpt);
  k_attn<<<dim3(NFULL), 256, 0, stream>>>(QHP, KH, Vt, Kp, Vpt, out);
}